// Round 3
// baseline (685.761 us; speedup 1.0000x reference)
//
#include <hip/hip_runtime.h>
#include <math.h>

// Problem constants: B=16, N=1024, F=64, T=24, K=3, FO=64
#define Bc 16
#define Nc 1024
#define Fc 64
#define Tc 24
#define Kc 3
#define FOc 64
#define Cc (Fc*Tc)      // 1536
#define KKc (Kc*Nc)     // 3072 = fused reduction length

typedef __attribute__((ext_vector_type(8))) short short8;   // 8 bf16 (4 VGPRs)
typedef __attribute__((ext_vector_type(8))) unsigned short u16x8;
typedef __attribute__((ext_vector_type(4))) float f32x4;

__device__ __forceinline__ unsigned short f2bf(float f) {
  unsigned u = __float_as_uint(f);
  u += 0x7fff + ((u >> 16) & 1);   // round-to-nearest-even
  return (unsigned short)(u >> 16);
}
__device__ __forceinline__ float bf2f(unsigned short h) {
  return __uint_as_float((unsigned)h << 16);
}

#define GLL16(g, l) __builtin_amdgcn_global_load_lds( \
    (const __attribute__((address_space(1))) void*)(g), \
    (__attribute__((address_space(3))) void*)(l), 16, 0, 0)

__device__ __forceinline__ f32x4 mfma16(short8 a, short8 b, f32x4 c) {
  return __builtin_amdgcn_mfma_f32_16x16x32_bf16(a, b, c, 0, 0, 0);
}

// ---------------------------------------------------------------------------
// Shared helpers: 128x128 tile, BK=64, XOR-swizzled LDS (conflict-free).
// ---------------------------------------------------------------------------
__device__ __forceinline__ void stage_tile(
    const unsigned short* a0, const unsigned short* b0,
    int lda, int ldb, int k0,
    unsigned short* asw, unsigned short* bsw) {
  #pragma unroll
  for (int c = 0; c < 4; ++c) {
    GLL16(a0 + (size_t)(c * 8) * lda + k0, asw + (c * 8) * 64);
    GLL16(b0 + (size_t)(c * 8) * ldb + k0, bsw + (c * 8) * 64);
  }
}

__device__ __forceinline__ void compute_tile(
    const unsigned short* As, const unsigned short* Bs,
    int rw, int cw, int frow, int p0, int p1, f32x4 acc[4][4]) {
  #pragma unroll
  for (int h = 0; h < 2; ++h) {
    int p = h ? p1 : p0;
    short8 afr[4], bfr[4];
    #pragma unroll
    for (int i = 0; i < 4; ++i)
      afr[i] = *(const short8*)&As[(rw + i * 16 + frow) * 64 + p];
    #pragma unroll
    for (int j = 0; j < 4; ++j)
      bfr[j] = *(const short8*)&Bs[(cw + j * 16 + frow) * 64 + p];
    #pragma unroll
    for (int i = 0; i < 4; ++i)
      #pragma unroll
      for (int j = 0; j < 4; ++j)
        acc[i][j] = mfma16(afr[i], bfr[j], acc[i][j]);
  }
}

// ---------------------------------------------------------------------------
// Single-buffer core (kept for y2: K=64, occupancy-sensitive).
// ---------------------------------------------------------------------------
__device__ __forceinline__ void gemm_core(
    const unsigned short* __restrict__ Ag, const unsigned short* __restrict__ Bg,
    int lda, int ldb, int K,
    unsigned short* As, unsigned short* Bs,
    int wave, int lane, f32x4 acc[4][4]) {
  int sr = lane >> 3;                    // row within a 1KB staging call
  int sc = ((lane & 7) ^ sr) * 8;        // swizzled source column (elems)
  const unsigned short* a0 = Ag + (size_t)(wave * 32 + sr) * lda + sc;
  const unsigned short* b0 = Bg + (size_t)(wave * 32 + sr) * ldb + sc;
  unsigned short* asw = As + (wave * 32) * 64;
  unsigned short* bsw = Bs + (wave * 32) * 64;
  int rw = (wave >> 1) * 64, cw = (wave & 1) * 64;
  int frow = lane & 15;
  int q = lane >> 4;
  int p0 = (q ^ (frow & 7)) * 8;         // half 0 chunk offset (elems)
  int p1 = ((q | 4) ^ (frow & 7)) * 8;   // half 1
  for (int k0 = 0; k0 < K; k0 += 64) {
    stage_tile(a0, b0, lda, ldb, k0, asw, bsw);
    __syncthreads();
    compute_tile(As, Bs, rw, cw, frow, p0, p1, acc);
    __syncthreads();
  }
}

// ---------------------------------------------------------------------------
// Double-buffered core (T3-minimum): stage tile k+1 into the alternate LDS
// buffer BEFORE computing tile k; one barrier per K-step. Load latency hides
// under the 32-MFMA compute phase instead of depending on co-resident blocks.
// S layout (64 KB): [As0 | Bs0 | As1 | Bs1], 16 KB each. K even mult of 64;
// the 2-step unroll keeps buffer selection compile-time (no runtime select).
// ---------------------------------------------------------------------------
__device__ __forceinline__ void gemm_core_db(
    const unsigned short* __restrict__ Ag, const unsigned short* __restrict__ Bg,
    int lda, int ldb, int K, unsigned short* S,
    int wave, int lane, f32x4 acc[4][4]) {
  int sr = lane >> 3;
  int sc = ((lane & 7) ^ sr) * 8;
  const unsigned short* a0 = Ag + (size_t)(wave * 32 + sr) * lda + sc;
  const unsigned short* b0 = Bg + (size_t)(wave * 32 + sr) * ldb + sc;
  int woff = (wave * 32) * 64;
  unsigned short* As0w = S + woff;
  unsigned short* Bs0w = S + 8192 + woff;
  unsigned short* As1w = S + 16384 + woff;
  unsigned short* Bs1w = S + 24576 + woff;
  int rw = (wave >> 1) * 64, cw = (wave & 1) * 64;
  int frow = lane & 15;
  int q = lane >> 4;
  int p0 = (q ^ (frow & 7)) * 8;
  int p1 = ((q | 4) ^ (frow & 7)) * 8;

  stage_tile(a0, b0, lda, ldb, 0, As0w, Bs0w);
  __syncthreads();
  int k0 = 0;
  for (;;) {
    // compute buf0, prefetch k0+64 into buf1
    if (k0 + 64 < K) stage_tile(a0, b0, lda, ldb, k0 + 64, As1w, Bs1w);
    compute_tile(S, S + 8192, rw, cw, frow, p0, p1, acc);
    __syncthreads();
    k0 += 64;
    if (k0 >= K) break;
    // compute buf1, prefetch k0+64 into buf0
    if (k0 + 64 < K) stage_tile(a0, b0, lda, ldb, k0 + 64, As0w, Bs0w);
    compute_tile(S + 16384, S + 24576, rw, cw, frow, p0, p1, acc);
    __syncthreads();
    k0 += 64;
    if (k0 >= K) break;
  }
}

// ---------------------------------------------------------------------------
// xprep: single pass over x producing xt2[b][n][t][f] (bf16) AND
// lhsb/rhsb (bf16, K-padded to 64 with zeros) for the MFMA attention GEMM.
// ---------------------------------------------------------------------------
__global__ __launch_bounds__(256) void xprep_kernel(
    const float* __restrict__ x, const float* __restrict__ W1,
    const float* __restrict__ W2, const float* __restrict__ W3,
    unsigned short* __restrict__ xt2, unsigned short* __restrict__ lhsb,
    unsigned short* __restrict__ rhsb) {
  __shared__ float ld[4 * 1560];   // per wave: [t][f] stride 65 (pad)
  __shared__ float af[4 * 64];
  int w = threadIdx.x >> 6, lane = threadIdx.x & 63;
  size_t n = (size_t)blockIdx.x * 4 + w;
  const float* xp = x + n * Cc;
  float* lw = ld + w * 1560;
  #pragma unroll
  for (int j = 0; j < 24; ++j) {
    int i = j * 64 + lane;
    int f = i / 24, t = i - f * 24;
    lw[t * 65 + f] = xp[i];
  }
  __syncthreads();
  float a = 0.f;
  #pragma unroll
  for (int t = 0; t < Tc; ++t) a += lw[t * 65 + lane] * W1[t];
  af[w * 64 + lane] = a;
  #pragma unroll
  for (int j = 0; j < 24; ++j)
    xt2[n * Cc + j * 64 + lane] = f2bf(lw[j * 65 + lane]);
  __syncthreads();
  float l = 0.f, r = 0.f;
  if (lane < Tc) {
    #pragma unroll 8
    for (int f = 0; f < Fc; ++f) {
      l += af[w * 64 + f] * W2[f * Tc + lane];
      r += W3[f] * lw[lane * 65 + f];
    }
  }
  lhsb[n * 64 + lane] = (lane < Tc) ? f2bf(l) : (unsigned short)0;
  rhsb[n * 64 + lane] = (lane < Tc) ? f2bf(r) : (unsigned short)0;
}

// ---------------------------------------------------------------------------
// misc: Vs->bf16 (blocks 0..1023), tcat (1024..1087), bsT transpose (1088..1343)
// ---------------------------------------------------------------------------
__global__ __launch_bounds__(256) void misc_kernel(
    const float* __restrict__ Vs, const float* __restrict__ Theta,
    const float* __restrict__ bs, unsigned short* __restrict__ Vsbf,
    unsigned short* __restrict__ tcat, float* __restrict__ bsT) {
  __shared__ float t[64 * 65];
  int bid = blockIdx.x, tid = threadIdx.x;
  if (bid < 1024) {
    int i = (bid * 256 + tid) * 4;
    float4 v = *(const float4*)&Vs[i];
    ushort4 o;
    o.x = f2bf(v.x); o.y = f2bf(v.y); o.z = f2bf(v.z); o.w = f2bf(v.w);
    *(ushort4*)&Vsbf[i] = o;
  } else if (bid < 1088) {
    int i = (bid - 1024) * 256 + tid;   // 0..16383
    int m2 = i >> 6, f = i & 63;
    int k = m2 >> 6, o = m2 & 63;
    tcat[i] = (m2 < 192) ? f2bf(Theta[((size_t)k * Fc + f) * FOc + o])
                         : (unsigned short)0;
  } else {
    int id = bid - 1088;                 // 0..255: bsT[p][q] = bs[q][p]
    int p0 = (id >> 4) * 64, q0 = (id & 15) * 64;
    #pragma unroll
    for (int s = 0; s < 4; ++s) {
      int qr = (tid >> 4) + s * 16, pc = (tid & 15) * 4;
      float4 v = *(const float4*)&bs[(size_t)(q0 + qr) * Nc + p0 + pc];
      t[(pc + 0) * 65 + qr] = v.x;
      t[(pc + 1) * 65 + qr] = v.y;
      t[(pc + 2) * 65 + qr] = v.z;
      t[(pc + 3) * 65 + qr] = v.w;
    }
    __syncthreads();
    #pragma unroll
    for (int s = 0; s < 4; ++s) {
      int pr = (tid >> 4) + s * 16, qc = (tid & 15) * 4;
      float4 v = {t[pr * 65 + qc], t[pr * 65 + qc + 1],
                  t[pr * 65 + qc + 2], t[pr * 65 + qc + 3]};
      *(float4*)&bsT[(size_t)(p0 + pr) * Nc + q0 + qc] = v;
    }
  }
}

// ---------------------------------------------------------------------------
// chebT[k][m][n] = cheb[k][n][m] (fp32 transpose)
// ---------------------------------------------------------------------------
__global__ __launch_bounds__(256) void chebT_kernel(
    const float* __restrict__ cheb, float* __restrict__ chebT) {
  int k = blockIdx.z;
  int n0 = blockIdx.y * 64, m0 = blockIdx.x * 64;
  __shared__ float t[64 * 65];
  const float* src = cheb + (size_t)k * Nc * Nc;
  float* dst = chebT + (size_t)k * Nc * Nc;
  int tid = threadIdx.x;
  #pragma unroll
  for (int s = 0; s < 4; ++s) {
    int nr = (tid >> 4) + s * 16, mc = (tid & 15) * 4;
    float4 v = *(const float4*)&src[(size_t)(n0 + nr) * Nc + m0 + mc];
    t[(mc + 0) * 65 + nr] = v.x;
    t[(mc + 1) * 65 + nr] = v.y;
    t[(mc + 2) * 65 + nr] = v.z;
    t[(mc + 3) * 65 + nr] = v.w;
  }
  __syncthreads();
  #pragma unroll
  for (int s = 0; s < 4; ++s) {
    int mr = (tid >> 4) + s * 16, nc = (tid & 15) * 4;
    float4 v = {t[mr * 65 + nc], t[mr * 65 + nc + 1], t[mr * 65 + nc + 2], t[mr * 65 + nc + 3]};
    *(float4*)&dst[(size_t)(m0 + mr) * Nc + n0 + nc] = v;
  }
}

// ---------------------------------------------------------------------------
// masksoft: per (bl,m) row of ST: softmax over n (fp32), then
// Acat[bl][m][k*1024+n] = bf16(chebT[k][m][n] * softmax_n)
// ---------------------------------------------------------------------------
__global__ __launch_bounds__(256) void masksoft_kernel(
    const float* __restrict__ chebT, const unsigned short* __restrict__ ST,
    unsigned short* __restrict__ Acat, int bbase) {
  int m  = blockIdx.x & (Nc - 1);
  int bl = blockIdx.x >> 10;
  int tid = threadIdx.x;
  const unsigned short* sp = ST + ((size_t)(bbase + bl) * Nc + m) * Nc;
  ushort4 s4 = *(const ushort4*)(sp + tid * 4);
  float v0 = bf2f(s4.x), v1 = bf2f(s4.y), v2 = bf2f(s4.z), v3 = bf2f(s4.w);
  __shared__ float redm[4], reds[4];
  int wave = tid >> 6, lane = tid & 63;
  float mx = fmaxf(fmaxf(v0, v1), fmaxf(v2, v3));
  #pragma unroll
  for (int off = 32; off; off >>= 1) mx = fmaxf(mx, __shfl_xor(mx, off));
  if (lane == 0) redm[wave] = mx;
  __syncthreads();
  mx = fmaxf(fmaxf(redm[0], redm[1]), fmaxf(redm[2], redm[3]));
  float e0 = __expf(v0 - mx), e1 = __expf(v1 - mx);
  float e2 = __expf(v2 - mx), e3 = __expf(v3 - mx);
  float sm = e0 + e1 + e2 + e3;
  #pragma unroll
  for (int off = 32; off; off >>= 1) sm += __shfl_xor(sm, off);
  if (lane == 0) reds[wave] = sm;
  __syncthreads();
  float inv = 1.f / (reds[0] + reds[1] + reds[2] + reds[3]);
  e0 *= inv; e1 *= inv; e2 *= inv; e3 *= inv;
  unsigned short* ap = Acat + ((size_t)bl * Nc + m) * KKc + tid * 4;
  #pragma unroll
  for (int k = 0; k < Kc; ++k) {
    float4 c = *(const float4*)&chebT[((size_t)k * Nc + m) * Nc + tid * 4];
    ushort4 o;
    o.x = f2bf(c.x * e0); o.y = f2bf(c.y * e1);
    o.z = f2bf(c.z * e2); o.w = f2bf(c.w * e3);
    *(ushort4*)(ap + k * Nc) = o;
  }
}

// ---------------------------------------------------------------------------
// MFMA GEMM: C[m][n] = sum_k A[m][k]*B[n][k].
// MODE 0: bf16 C. MODE 1: fp32 relu C. MODE 2: bf16 sigmoid(C + bias[m][n]).
// XCD-aware bijective swizzle (m204) + double-buffered K-loop (T3-minimum).
// ---------------------------------------------------------------------------
template <int MODE>
__global__ __launch_bounds__(256) void mfma_gemm_bt(
    const unsigned short* __restrict__ A, const unsigned short* __restrict__ B,
    void* __restrict__ Cv, const float* __restrict__ bias, int K, int CN,
    long long Abatch, long long Bbatch, long long Cbatch) {
  __shared__ unsigned short S[4 * 128 * 64];   // 64 KB: As0|Bs0|As1|Bs1
  int gx = gridDim.x, gy = gridDim.y;
  int nwg = gx * gy * gridDim.z;
  int bid = blockIdx.x + gx * (blockIdx.y + gy * blockIdx.z);
  int xcd = bid & 7, idx = bid >> 3;
  int qq = nwg >> 3, rr = nwg & 7;
  int lin = (xcd < rr ? xcd * (qq + 1) : rr * (qq + 1) + (xcd - rr) * qq) + idx;
  int b = lin / (gx * gy);
  int rem = lin - b * (gx * gy);
  int by = rem / gx, bx = rem - by * gx;
  int tid = threadIdx.x, wave = tid >> 6, lane = tid & 63;
  const unsigned short* Ag = A + (size_t)b * Abatch + (size_t)by * 128 * K;
  const unsigned short* Bg = B + (size_t)b * Bbatch + (size_t)bx * 128 * K;
  f32x4 zero = {0.f, 0.f, 0.f, 0.f};
  f32x4 acc[4][4];
  #pragma unroll
  for (int i = 0; i < 4; ++i)
    #pragma unroll
    for (int j = 0; j < 4; ++j) acc[i][j] = zero;
  gemm_core_db(Ag, Bg, K, K, K, S, wave, lane, acc);
  int rw = (wave >> 1) * 64, cw = (wave & 1) * 64;
  int q = lane >> 4, cl = lane & 15;
  #pragma unroll
  for (int i = 0; i < 4; ++i)
    #pragma unroll
    for (int e = 0; e < 4; ++e) {
      size_t P = (size_t)by * 128 + rw + i * 16 + q * 4 + e;
      #pragma unroll
      for (int j = 0; j < 4; ++j) {
        size_t Q = (size_t)bx * 128 + cw + j * 16 + cl;
        if (MODE == 0) {
          ((unsigned short*)Cv)[(size_t)b * Cbatch + P * CN + Q] = f2bf(acc[i][j][e]);
        } else if (MODE == 1) {
          ((float*)Cv)[(size_t)b * Cbatch + P * CN + Q] = fmaxf(acc[i][j][e], 0.f);
        } else {
          float v = acc[i][j][e] + bias[P * CN + Q];
          ((unsigned short*)Cv)[(size_t)b * Cbatch + P * CN + Q] =
              f2bf(1.f / (1.f + __expf(-v)));
        }
      }
    }
}

// ---------------------------------------------------------------------------
// y2 GEMM: for z=(bl,t): ycat[bl][(o*24+t)][k*1024+n] =
//   sum_f tcat[(k*64+o)][f] * xt2[bbase+bl][n][t][f].  K=64.
// ---------------------------------------------------------------------------
__global__ __launch_bounds__(256) void y2_gemm(
    const unsigned short* __restrict__ tcat, const unsigned short* __restrict__ xt2,
    unsigned short* __restrict__ ycat, int bbase) {
  __shared__ unsigned short As[128 * 64];
  __shared__ unsigned short Bs[128 * 64];
  int z = blockIdx.z;
  int bl = z / 24, t = z - bl * 24;
  int tid = threadIdx.x, wave = tid >> 6, lane = tid & 63;
  const unsigned short* Ag = tcat + (size_t)blockIdx.y * 128 * 64;
  const unsigned short* Bg = xt2 + ((size_t)(bbase + bl) * Nc + (size_t)blockIdx.x * 128) * Cc
                             + (size_t)t * 64;
  f32x4 zero = {0.f, 0.f, 0.f, 0.f};
  f32x4 acc[4][4];
  #pragma unroll
  for (int i = 0; i < 4; ++i)
    #pragma unroll
    for (int j = 0; j < 4; ++j) acc[i][j] = zero;
  gemm_core(Ag, Bg, 64, Cc, 64, As, Bs, wave, lane, acc);
  int rw = (wave >> 1) * 64, cw = (wave & 1) * 64;
  int q = lane >> 4, cl = lane & 15;
  unsigned short* yb = ycat + (size_t)bl * Cc * KKc + (size_t)t * KKc;
  #pragma unroll
  for (int i = 0; i < 4; ++i)
    #pragma unroll
    for (int e = 0; e < 4; ++e) {
      int m2 = blockIdx.y * 128 + rw + i * 16 + q * 4 + e;
      if (m2 < 192) {
        int kk = m2 >> 6, o = m2 & 63;
        unsigned short* dst = yb + (size_t)o * 24 * KKc + kk * Nc;
        #pragma unroll
        for (int j = 0; j < 4; ++j)
          dst[blockIdx.x * 128 + cw + j * 16 + cl] = f2bf(acc[i][j][e]);
      }
    }
}

// ---------------------------------------------------------------------------
extern "C" void kernel_launch(void* const* d_in, const int* in_sizes, int n_in,
                              void* d_out, int out_size, void* d_ws, size_t ws_size,
                              hipStream_t stream) {
  const float* x     = (const float*)d_in[0];
  const float* W1    = (const float*)d_in[1];
  const float* W2    = (const float*)d_in[2];
  const float* W3    = (const float*)d_in[3];
  const float* bs    = (const float*)d_in[4];
  const float* Vs    = (const float*)d_in[5];
  const float* cheb  = (const float*)d_in[6];
  const float* Theta = (const float*)d_in[7];
  float* out = (float*)d_out;

  // ws_size-adaptive: 1 pass of 16 batches (needs 348.2 MB) or 2 passes of 8
  // (needs 222.3 MB, the R4-verified layout). Deterministic per harness.
  int passes, blcount;
  if (ws_size >= 348160000ULL) { passes = 1; blcount = 16; }
  else                         { passes = 2; blcount = 8;  }

  char* w = (char*)d_ws;
  size_t Y  = (size_t)blcount * Cc * KKc * 2;   // ycat bytes
  size_t A2 = (size_t)blcount * Nc * KKc * 2;   // Acat bytes
  unsigned short* ycat = (unsigned short*)w;
  unsigned short* Acat = (unsigned short*)(w + Y);
  unsigned short* ST   = (unsigned short*)(w + Y + A2);                 // 33.55 MB
  float* chebT         = (float*)(w + Y + A2 + 33554432);               // 12.58 MB
  unsigned short* xt2  = (unsigned short*)(w + Y + A2 + 46137344);      // 50.33 MB
  unsigned short* tcat = (unsigned short*)(w + Y + A2 + 96468992);      // 32 KB
  // Front-phase temps aliased into ycat (all dead before y2 writes ycat):
  unsigned short* lhsb = (unsigned short*)w;                // 2 MB
  unsigned short* rhsb = (unsigned short*)(w + 2097152);    // 2 MB
  unsigned short* sigT = (unsigned short*)(w + 4194304);    // 33.55 MB
  float* bsT           = (float*)(w + 37748736);            // 4.19 MB
  unsigned short* Vsbf = (unsigned short*)(w + 41943040);   // 2 MB (ends 44.04 MB <= 75.5)

  xprep_kernel<<<Bc * Nc / 4, 256, 0, stream>>>(x, W1, W2, W3, xt2, lhsb, rhsb);
  misc_kernel<<<1344, 256, 0, stream>>>(Vs, Theta, bs, Vsbf, tcat, bsT);
  // sigT[p][q] = sigmoid(sum_t rhsb[p,t]*lhsb[q,t] + bsT[p][q])
  mfma_gemm_bt<2><<<dim3(8, 8, 16), 256, 0, stream>>>(
      rhsb, lhsb, sigT, bsT, 64, Nc,
      (long long)Nc * 64, (long long)Nc * 64, (long long)Nc * Nc);
  // ST[b][j][i] = sum_kk sigT[b][j][kk] * Vs[i][kk]
  mfma_gemm_bt<0><<<dim3(8, 8, 16), 256, 0, stream>>>(
      sigT, Vsbf, ST, nullptr, Nc, Nc,
      (long long)Nc * Nc, 0LL, (long long)Nc * Nc);
  chebT_kernel<<<dim3(16, 16, 3), 256, 0, stream>>>(cheb, chebT);

  for (int pass = 0; pass < passes; ++pass) {
    int bbase = pass * blcount;
    masksoft_kernel<<<blcount * Nc, 256, 0, stream>>>(chebT, ST, Acat, bbase);
    y2_gemm<<<dim3(Nc / 128, 2, blcount * 24), 256, 0, stream>>>(tcat, xt2, ycat, bbase);
    // out[b][m][o*24+t] = relu( sum_{kk<3072} Acat[bl][m][kk] * ycat[bl][c''][kk] )
    mfma_gemm_bt<1><<<dim3(Cc / 128, Nc / 128, blcount), 256, 0, stream>>>(
        Acat, ycat, out + (size_t)bbase * Nc * Cc, nullptr, KKc, Cc,
        (long long)Nc * KKc, (long long)Cc * KKc, (long long)Nc * Cc);
  }
}

// Round 4
// 579.799 us; speedup vs baseline: 1.1828x; 1.1828x over previous
//
#include <hip/hip_runtime.h>
#include <math.h>

// Problem constants: B=16, N=1024, F=64, T=24, K=3, FO=64
#define Bc 16
#define Nc 1024
#define Fc 64
#define Tc 24
#define Kc 3
#define FOc 64
#define Cc (Fc*Tc)      // 1536
#define KKc (Kc*Nc)     // 3072 = fused reduction length

typedef __attribute__((ext_vector_type(8))) short short8;   // 8 bf16 (4 VGPRs)
typedef __attribute__((ext_vector_type(8))) unsigned short u16x8;
typedef __attribute__((ext_vector_type(4))) float f32x4;

__device__ __forceinline__ unsigned short f2bf(float f) {
  unsigned u = __float_as_uint(f);
  u += 0x7fff + ((u >> 16) & 1);   // round-to-nearest-even
  return (unsigned short)(u >> 16);
}
__device__ __forceinline__ float bf2f(unsigned short h) {
  return __uint_as_float((unsigned)h << 16);
}

#define GLL16(g, l) __builtin_amdgcn_global_load_lds( \
    (const __attribute__((address_space(1))) void*)(g), \
    (__attribute__((address_space(3))) void*)(l), 16, 0, 0)

__device__ __forceinline__ f32x4 mfma16(short8 a, short8 b, f32x4 c) {
  return __builtin_amdgcn_mfma_f32_16x16x32_bf16(a, b, c, 0, 0, 0);
}

// ---------------------------------------------------------------------------
// Single-buffer 128x128 core (y2 only). XOR-swizzled LDS, conflict-free.
// ---------------------------------------------------------------------------
__device__ __forceinline__ void gemm_core(
    const unsigned short* __restrict__ Ag, const unsigned short* __restrict__ Bg,
    int lda, int ldb, int K,
    unsigned short* As, unsigned short* Bs,
    int wave, int lane, f32x4 acc[4][4]) {
  int sr = lane >> 3;                    // row within a 1KB staging call
  int sc = ((lane & 7) ^ sr) * 8;        // swizzled source column (elems)
  const unsigned short* a0 = Ag + (size_t)(wave * 32 + sr) * lda + sc;
  const unsigned short* b0 = Bg + (size_t)(wave * 32 + sr) * ldb + sc;
  unsigned short* asw = As + (wave * 32) * 64;
  unsigned short* bsw = Bs + (wave * 32) * 64;
  int rw = (wave >> 1) * 64, cw = (wave & 1) * 64;
  int frow = lane & 15;
  int q = lane >> 4;
  int p0 = (q ^ (frow & 7)) * 8;         // half 0 chunk offset (elems)
  int p1 = ((q | 4) ^ (frow & 7)) * 8;   // half 1
  for (int k0 = 0; k0 < K; k0 += 64) {
    #pragma unroll
    for (int c = 0; c < 4; ++c) {
      GLL16(a0 + (size_t)(c * 8) * lda + k0, asw + (c * 8) * 64);
      GLL16(b0 + (size_t)(c * 8) * ldb + k0, bsw + (c * 8) * 64);
    }
    __syncthreads();
    #pragma unroll
    for (int h = 0; h < 2; ++h) {
      int p = h ? p1 : p0;
      short8 afr[4], bfr[4];
      #pragma unroll
      for (int i = 0; i < 4; ++i)
        afr[i] = *(const short8*)&As[(rw + i * 16 + frow) * 64 + p];
      #pragma unroll
      for (int j = 0; j < 4; ++j)
        bfr[j] = *(const short8*)&Bs[(cw + j * 16 + frow) * 64 + p];
      #pragma unroll
      for (int i = 0; i < 4; ++i)
        #pragma unroll
        for (int j = 0; j < 4; ++j)
          acc[i][j] = mfma16(afr[i], bfr[j], acc[i][j]);
    }
    __syncthreads();
  }
}

// ---------------------------------------------------------------------------
// Single-buffer 128x64 core: 24 KB LDS -> 6 blocks/CU (vs 3 at 128x128).
// TLP is the dominant lever in this 2-barrier structure (m102 scaling);
// same staging swizzle, same read swizzle (row&7 == frow&7 for all rows).
// Waves 2x2 over (128,64): each computes 64x32 via acc[4][2].
// ---------------------------------------------------------------------------
__device__ __forceinline__ void gemm_core_n64(
    const unsigned short* __restrict__ Ag, const unsigned short* __restrict__ Bg,
    int lda, int ldb, int K,
    unsigned short* As, unsigned short* Bs,
    int wave, int lane, f32x4 acc[4][2]) {
  int sr = lane >> 3;
  int sc = ((lane & 7) ^ sr) * 8;
  const unsigned short* a0 = Ag + (size_t)(wave * 32 + sr) * lda + sc;
  const unsigned short* b0 = Bg + (size_t)(wave * 16 + sr) * ldb + sc;
  unsigned short* asw = As + (wave * 32) * 64;
  unsigned short* bsw = Bs + (wave * 16) * 64;
  int rw = (wave >> 1) * 64, cw = (wave & 1) * 32;
  int frow = lane & 15;
  int q = lane >> 4;
  int p0 = (q ^ (frow & 7)) * 8;
  int p1 = ((q | 4) ^ (frow & 7)) * 8;
  for (int k0 = 0; k0 < K; k0 += 64) {
    #pragma unroll
    for (int c = 0; c < 4; ++c)
      GLL16(a0 + (size_t)(c * 8) * lda + k0, asw + (c * 8) * 64);
    #pragma unroll
    for (int c = 0; c < 2; ++c)
      GLL16(b0 + (size_t)(c * 8) * ldb + k0, bsw + (c * 8) * 64);
    __syncthreads();
    #pragma unroll
    for (int h = 0; h < 2; ++h) {
      int p = h ? p1 : p0;
      short8 afr[4], bfr[2];
      #pragma unroll
      for (int i = 0; i < 4; ++i)
        afr[i] = *(const short8*)&As[(rw + i * 16 + frow) * 64 + p];
      #pragma unroll
      for (int j = 0; j < 2; ++j)
        bfr[j] = *(const short8*)&Bs[(cw + j * 16 + frow) * 64 + p];
      #pragma unroll
      for (int i = 0; i < 4; ++i)
        #pragma unroll
        for (int j = 0; j < 2; ++j)
          acc[i][j] = mfma16(afr[i], bfr[j], acc[i][j]);
    }
    __syncthreads();
  }
}

// ---------------------------------------------------------------------------
// xprep: single pass over x producing xt2[b][n][t][f] (bf16) AND
// lhsb/rhsb (bf16, K-padded to 64 with zeros) for the MFMA attention GEMM.
// ---------------------------------------------------------------------------
__global__ __launch_bounds__(256) void xprep_kernel(
    const float* __restrict__ x, const float* __restrict__ W1,
    const float* __restrict__ W2, const float* __restrict__ W3,
    unsigned short* __restrict__ xt2, unsigned short* __restrict__ lhsb,
    unsigned short* __restrict__ rhsb) {
  __shared__ float ld[4 * 1560];   // per wave: [t][f] stride 65 (pad)
  __shared__ float af[4 * 64];
  int w = threadIdx.x >> 6, lane = threadIdx.x & 63;
  size_t n = (size_t)blockIdx.x * 4 + w;
  const float* xp = x + n * Cc;
  float* lw = ld + w * 1560;
  #pragma unroll
  for (int j = 0; j < 24; ++j) {
    int i = j * 64 + lane;
    int f = i / 24, t = i - f * 24;
    lw[t * 65 + f] = xp[i];
  }
  __syncthreads();
  float a = 0.f;
  #pragma unroll
  for (int t = 0; t < Tc; ++t) a += lw[t * 65 + lane] * W1[t];
  af[w * 64 + lane] = a;
  #pragma unroll
  for (int j = 0; j < 24; ++j)
    xt2[n * Cc + j * 64 + lane] = f2bf(lw[j * 65 + lane]);
  __syncthreads();
  float l = 0.f, r = 0.f;
  if (lane < Tc) {
    #pragma unroll 8
    for (int f = 0; f < Fc; ++f) {
      l += af[w * 64 + f] * W2[f * Tc + lane];
      r += W3[f] * lw[lane * 65 + f];
    }
  }
  lhsb[n * 64 + lane] = (lane < Tc) ? f2bf(l) : (unsigned short)0;
  rhsb[n * 64 + lane] = (lane < Tc) ? f2bf(r) : (unsigned short)0;
}

// ---------------------------------------------------------------------------
// misc: Vs->bf16 (blocks 0..1023), tcat (1024..1087), bsT transpose (1088..1343)
// ---------------------------------------------------------------------------
__global__ __launch_bounds__(256) void misc_kernel(
    const float* __restrict__ Vs, const float* __restrict__ Theta,
    const float* __restrict__ bs, unsigned short* __restrict__ Vsbf,
    unsigned short* __restrict__ tcat, float* __restrict__ bsT) {
  __shared__ float t[64 * 65];
  int bid = blockIdx.x, tid = threadIdx.x;
  if (bid < 1024) {
    int i = (bid * 256 + tid) * 4;
    float4 v = *(const float4*)&Vs[i];
    ushort4 o;
    o.x = f2bf(v.x); o.y = f2bf(v.y); o.z = f2bf(v.z); o.w = f2bf(v.w);
    *(ushort4*)&Vsbf[i] = o;
  } else if (bid < 1088) {
    int i = (bid - 1024) * 256 + tid;   // 0..16383
    int m2 = i >> 6, f = i & 63;
    int k = m2 >> 6, o = m2 & 63;
    tcat[i] = (m2 < 192) ? f2bf(Theta[((size_t)k * Fc + f) * FOc + o])
                         : (unsigned short)0;
  } else {
    int id = bid - 1088;                 // 0..255: bsT[p][q] = bs[q][p]
    int p0 = (id >> 4) * 64, q0 = (id & 15) * 64;
    #pragma unroll
    for (int s = 0; s < 4; ++s) {
      int qr = (tid >> 4) + s * 16, pc = (tid & 15) * 4;
      float4 v = *(const float4*)&bs[(size_t)(q0 + qr) * Nc + p0 + pc];
      t[(pc + 0) * 65 + qr] = v.x;
      t[(pc + 1) * 65 + qr] = v.y;
      t[(pc + 2) * 65 + qr] = v.z;
      t[(pc + 3) * 65 + qr] = v.w;
    }
    __syncthreads();
    #pragma unroll
    for (int s = 0; s < 4; ++s) {
      int pr = (tid >> 4) + s * 16, qc = (tid & 15) * 4;
      float4 v = {t[pr * 65 + qc], t[pr * 65 + qc + 1],
                  t[pr * 65 + qc + 2], t[pr * 65 + qc + 3]};
      *(float4*)&bsT[(size_t)(p0 + pr) * Nc + q0 + qc] = v;
    }
  }
}

// ---------------------------------------------------------------------------
// chebT[k][m][n] = cheb[k][n][m] (fp32 transpose)
// ---------------------------------------------------------------------------
__global__ __launch_bounds__(256) void chebT_kernel(
    const float* __restrict__ cheb, float* __restrict__ chebT) {
  int k = blockIdx.z;
  int n0 = blockIdx.y * 64, m0 = blockIdx.x * 64;
  __shared__ float t[64 * 65];
  const float* src = cheb + (size_t)k * Nc * Nc;
  float* dst = chebT + (size_t)k * Nc * Nc;
  int tid = threadIdx.x;
  #pragma unroll
  for (int s = 0; s < 4; ++s) {
    int nr = (tid >> 4) + s * 16, mc = (tid & 15) * 4;
    float4 v = *(const float4*)&src[(size_t)(n0 + nr) * Nc + m0 + mc];
    t[(mc + 0) * 65 + nr] = v.x;
    t[(mc + 1) * 65 + nr] = v.y;
    t[(mc + 2) * 65 + nr] = v.z;
    t[(mc + 3) * 65 + nr] = v.w;
  }
  __syncthreads();
  #pragma unroll
  for (int s = 0; s < 4; ++s) {
    int mr = (tid >> 4) + s * 16, nc = (tid & 15) * 4;
    float4 v = {t[mr * 65 + nc], t[mr * 65 + nc + 1], t[mr * 65 + nc + 2], t[mr * 65 + nc + 3]};
    *(float4*)&dst[(size_t)(m0 + mr) * Nc + n0 + nc] = v;
  }
}

// ---------------------------------------------------------------------------
// masksoft: per (bl,m) row of ST: softmax over n (fp32), then
// Acat[bl][m][k*1024+n] = bf16(chebT[k][m][n] * softmax_n)
// ---------------------------------------------------------------------------
__global__ __launch_bounds__(256) void masksoft_kernel(
    const float* __restrict__ chebT, const unsigned short* __restrict__ ST,
    unsigned short* __restrict__ Acat, int bbase) {
  int m  = blockIdx.x & (Nc - 1);
  int bl = blockIdx.x >> 10;
  int tid = threadIdx.x;
  const unsigned short* sp = ST + ((size_t)(bbase + bl) * Nc + m) * Nc;
  ushort4 s4 = *(const ushort4*)(sp + tid * 4);
  float v0 = bf2f(s4.x), v1 = bf2f(s4.y), v2 = bf2f(s4.z), v3 = bf2f(s4.w);
  __shared__ float redm[4], reds[4];
  int wave = tid >> 6, lane = tid & 63;
  float mx = fmaxf(fmaxf(v0, v1), fmaxf(v2, v3));
  #pragma unroll
  for (int off = 32; off; off >>= 1) mx = fmaxf(mx, __shfl_xor(mx, off));
  if (lane == 0) redm[wave] = mx;
  __syncthreads();
  mx = fmaxf(fmaxf(redm[0], redm[1]), fmaxf(redm[2], redm[3]));
  float e0 = __expf(v0 - mx), e1 = __expf(v1 - mx);
  float e2 = __expf(v2 - mx), e3 = __expf(v3 - mx);
  float sm = e0 + e1 + e2 + e3;
  #pragma unroll
  for (int off = 32; off; off >>= 1) sm += __shfl_xor(sm, off);
  if (lane == 0) reds[wave] = sm;
  __syncthreads();
  float inv = 1.f / (reds[0] + reds[1] + reds[2] + reds[3]);
  e0 *= inv; e1 *= inv; e2 *= inv; e3 *= inv;
  unsigned short* ap = Acat + ((size_t)bl * Nc + m) * KKc + tid * 4;
  #pragma unroll
  for (int k = 0; k < Kc; ++k) {
    float4 c = *(const float4*)&chebT[((size_t)k * Nc + m) * Nc + tid * 4];
    ushort4 o;
    o.x = f2bf(c.x * e0); o.y = f2bf(c.y * e1);
    o.z = f2bf(c.z * e2); o.w = f2bf(c.w * e3);
    *(ushort4*)(ap + k * Nc) = o;
  }
}

// ---------------------------------------------------------------------------
// MFMA GEMM, 128x64 tile: C[m][n] = sum_k A[m][k]*B[n][k].
// MODE 0: bf16 C. MODE 1: fp32 relu C. MODE 2: bf16 sigmoid(C + bias[m][n]).
// XCD-aware bijective swizzle (m204). 24 KB LDS -> 6 blocks/CU.
// ---------------------------------------------------------------------------
template <int MODE>
__global__ __launch_bounds__(256) void mfma_gemm_bt(
    const unsigned short* __restrict__ A, const unsigned short* __restrict__ B,
    void* __restrict__ Cv, const float* __restrict__ bias, int K, int CN,
    long long Abatch, long long Bbatch, long long Cbatch) {
  __shared__ unsigned short As[128 * 64];   // 16 KB
  __shared__ unsigned short Bs[64 * 64];    // 8 KB
  int gx = gridDim.x, gy = gridDim.y;
  int nwg = gx * gy * gridDim.z;
  int bid = blockIdx.x + gx * (blockIdx.y + gy * blockIdx.z);
  int xcd = bid & 7, idx = bid >> 3;
  int qq = nwg >> 3, rr = nwg & 7;
  int lin = (xcd < rr ? xcd * (qq + 1) : rr * (qq + 1) + (xcd - rr) * qq) + idx;
  int b = lin / (gx * gy);
  int rem = lin - b * (gx * gy);
  int by = rem / gx, bx = rem - by * gx;
  int tid = threadIdx.x, wave = tid >> 6, lane = tid & 63;
  const unsigned short* Ag = A + (size_t)b * Abatch + (size_t)by * 128 * K;
  const unsigned short* Bg = B + (size_t)b * Bbatch + (size_t)bx * 64 * K;
  f32x4 zero = {0.f, 0.f, 0.f, 0.f};
  f32x4 acc[4][2];
  #pragma unroll
  for (int i = 0; i < 4; ++i)
    #pragma unroll
    for (int j = 0; j < 2; ++j) acc[i][j] = zero;
  gemm_core_n64(Ag, Bg, K, K, K, As, Bs, wave, lane, acc);
  int rw = (wave >> 1) * 64, cw = (wave & 1) * 32;
  int q = lane >> 4, cl = lane & 15;
  #pragma unroll
  for (int i = 0; i < 4; ++i)
    #pragma unroll
    for (int e = 0; e < 4; ++e) {
      size_t P = (size_t)by * 128 + rw + i * 16 + q * 4 + e;
      #pragma unroll
      for (int j = 0; j < 2; ++j) {
        size_t Q = (size_t)bx * 64 + cw + j * 16 + cl;
        if (MODE == 0) {
          ((unsigned short*)Cv)[(size_t)b * Cbatch + P * CN + Q] = f2bf(acc[i][j][e]);
        } else if (MODE == 1) {
          ((float*)Cv)[(size_t)b * Cbatch + P * CN + Q] = fmaxf(acc[i][j][e], 0.f);
        } else {
          float v = acc[i][j][e] + bias[P * CN + Q];
          ((unsigned short*)Cv)[(size_t)b * Cbatch + P * CN + Q] =
              f2bf(1.f / (1.f + __expf(-v)));
        }
      }
    }
}

// ---------------------------------------------------------------------------
// y2 GEMM: for z=(bl,t): ycat[bl][(o*24+t)][k*1024+n] =
//   sum_f tcat[(k*64+o)][f] * xt2[bbase+bl][n][t][f].  K=64.
// ---------------------------------------------------------------------------
__global__ __launch_bounds__(256) void y2_gemm(
    const unsigned short* __restrict__ tcat, const unsigned short* __restrict__ xt2,
    unsigned short* __restrict__ ycat, int bbase) {
  __shared__ unsigned short As[128 * 64];
  __shared__ unsigned short Bs[128 * 64];
  int z = blockIdx.z;
  int bl = z / 24, t = z - bl * 24;
  int tid = threadIdx.x, wave = tid >> 6, lane = tid & 63;
  const unsigned short* Ag = tcat + (size_t)blockIdx.y * 128 * 64;
  const unsigned short* Bg = xt2 + ((size_t)(bbase + bl) * Nc + (size_t)blockIdx.x * 128) * Cc
                             + (size_t)t * 64;
  f32x4 zero = {0.f, 0.f, 0.f, 0.f};
  f32x4 acc[4][4];
  #pragma unroll
  for (int i = 0; i < 4; ++i)
    #pragma unroll
    for (int j = 0; j < 4; ++j) acc[i][j] = zero;
  gemm_core(Ag, Bg, 64, Cc, 64, As, Bs, wave, lane, acc);
  int rw = (wave >> 1) * 64, cw = (wave & 1) * 64;
  int q = lane >> 4, cl = lane & 15;
  unsigned short* yb = ycat + (size_t)bl * Cc * KKc + (size_t)t * KKc;
  #pragma unroll
  for (int i = 0; i < 4; ++i)
    #pragma unroll
    for (int e = 0; e < 4; ++e) {
      int m2 = blockIdx.y * 128 + rw + i * 16 + q * 4 + e;
      if (m2 < 192) {
        int kk = m2 >> 6, o = m2 & 63;
        unsigned short* dst = yb + (size_t)o * 24 * KKc + kk * Nc;
        #pragma unroll
        for (int j = 0; j < 4; ++j)
          dst[blockIdx.x * 128 + cw + j * 16 + cl] = f2bf(acc[i][j][e]);
      }
    }
}

// ---------------------------------------------------------------------------
extern "C" void kernel_launch(void* const* d_in, const int* in_sizes, int n_in,
                              void* d_out, int out_size, void* d_ws, size_t ws_size,
                              hipStream_t stream) {
  const float* x     = (const float*)d_in[0];
  const float* W1    = (const float*)d_in[1];
  const float* W2    = (const float*)d_in[2];
  const float* W3    = (const float*)d_in[3];
  const float* bs    = (const float*)d_in[4];
  const float* Vs    = (const float*)d_in[5];
  const float* cheb  = (const float*)d_in[6];
  const float* Theta = (const float*)d_in[7];
  float* out = (float*)d_out;

  // ws_size-adaptive: 1 pass of 16 batches (needs 348.2 MB) or 2 passes of 8
  // (needs 222.3 MB, the R4-verified layout). Deterministic per harness.
  int passes, blcount;
  if (ws_size >= 348160000ULL) { passes = 1; blcount = 16; }
  else                         { passes = 2; blcount = 8;  }

  char* w = (char*)d_ws;
  size_t Y  = (size_t)blcount * Cc * KKc * 2;   // ycat bytes
  size_t A2 = (size_t)blcount * Nc * KKc * 2;   // Acat bytes
  unsigned short* ycat = (unsigned short*)w;
  unsigned short* Acat = (unsigned short*)(w + Y);
  unsigned short* ST   = (unsigned short*)(w + Y + A2);                 // 33.55 MB
  float* chebT         = (float*)(w + Y + A2 + 33554432);               // 12.58 MB
  unsigned short* xt2  = (unsigned short*)(w + Y + A2 + 46137344);      // 50.33 MB
  unsigned short* tcat = (unsigned short*)(w + Y + A2 + 96468992);      // 32 KB
  // Front-phase temps aliased into ycat (all dead before y2 writes ycat):
  unsigned short* lhsb = (unsigned short*)w;                // 2 MB
  unsigned short* rhsb = (unsigned short*)(w + 2097152);    // 2 MB
  unsigned short* sigT = (unsigned short*)(w + 4194304);    // 33.55 MB
  float* bsT           = (float*)(w + 37748736);            // 4.19 MB
  unsigned short* Vsbf = (unsigned short*)(w + 41943040);   // 2 MB (ends 44.04 MB <= 75.5)

  xprep_kernel<<<Bc * Nc / 4, 256, 0, stream>>>(x, W1, W2, W3, xt2, lhsb, rhsb);
  misc_kernel<<<1344, 256, 0, stream>>>(Vs, Theta, bs, Vsbf, tcat, bsT);
  // sigT[p][q] = sigmoid(sum_t rhsb[p,t]*lhsb[q,t] + bsT[p][q])
  mfma_gemm_bt<2><<<dim3(16, 8, 16), 256, 0, stream>>>(
      rhsb, lhsb, sigT, bsT, 64, Nc,
      (long long)Nc * 64, (long long)Nc * 64, (long long)Nc * Nc);
  // ST[b][j][i] = sum_kk sigT[b][j][kk] * Vs[i][kk]
  mfma_gemm_bt<0><<<dim3(16, 8, 16), 256, 0, stream>>>(
      sigT, Vsbf, ST, nullptr, Nc, Nc,
      (long long)Nc * Nc, 0LL, (long long)Nc * Nc);
  chebT_kernel<<<dim3(16, 16, 3), 256, 0, stream>>>(cheb, chebT);

  for (int pass = 0; pass < passes; ++pass) {
    int bbase = pass * blcount;
    masksoft_kernel<<<blcount * Nc, 256, 0, stream>>>(chebT, ST, Acat, bbase);
    y2_gemm<<<dim3(Nc / 128, 2, blcount * 24), 256, 0, stream>>>(tcat, xt2, ycat, bbase);
    // out[b][m][o*24+t] = relu( sum_{kk<3072} Acat[bl][m][kk] * ycat[bl][c''][kk] )
    mfma_gemm_bt<1><<<dim3(Cc / 64, Nc / 128, blcount), 256, 0, stream>>>(
        Acat, ycat, out + (size_t)bbase * Nc * Cc, nullptr, KKc, Cc,
        (long long)Nc * KKc, (long long)Cc * KKc, (long long)Nc * Cc);
  }
}

// Round 5
// 577.093 us; speedup vs baseline: 1.1883x; 1.0047x over previous
//
#include <hip/hip_runtime.h>
#include <math.h>

// Problem constants: B=16, N=1024, F=64, T=24, K=3, FO=64
#define Bc 16
#define Nc 1024
#define Fc 64
#define Tc 24
#define Kc 3
#define FOc 64
#define Cc (Fc*Tc)      // 1536
#define KKc (Kc*Nc)     // 3072 = fused reduction length

typedef __attribute__((ext_vector_type(8))) short short8;   // 8 bf16 (4 VGPRs)
typedef __attribute__((ext_vector_type(4))) float f32x4;

__device__ __forceinline__ unsigned short f2bf(float f) {
  unsigned u = __float_as_uint(f);
  u += 0x7fff + ((u >> 16) & 1);   // round-to-nearest-even
  return (unsigned short)(u >> 16);
}
__device__ __forceinline__ float bf2f(unsigned short h) {
  return __uint_as_float((unsigned)h << 16);
}

#define GLL16(g, l) __builtin_amdgcn_global_load_lds( \
    (const __attribute__((address_space(1))) void*)(g), \
    (__attribute__((address_space(3))) void*)(l), 16, 0, 0)

__device__ __forceinline__ f32x4 mfma16(short8 a, short8 b, f32x4 c) {
  return __builtin_amdgcn_mfma_f32_16x16x32_bf16(a, b, c, 0, 0, 0);
}

// ---------------------------------------------------------------------------
// Single-buffer 128x128 core (sigT K=64 + y2). XOR-swizzled LDS, conflict-free.
// ---------------------------------------------------------------------------
__device__ __forceinline__ void gemm_core(
    const unsigned short* __restrict__ Ag, const unsigned short* __restrict__ Bg,
    int lda, int ldb, int K,
    unsigned short* As, unsigned short* Bs,
    int wave, int lane, f32x4 acc[4][4]) {
  int sr = lane >> 3;                    // row within a 1KB staging call
  int sc = ((lane & 7) ^ sr) * 8;        // swizzled source column (elems)
  const unsigned short* a0 = Ag + (size_t)(wave * 32 + sr) * lda + sc;
  const unsigned short* b0 = Bg + (size_t)(wave * 32 + sr) * ldb + sc;
  unsigned short* asw = As + (wave * 32) * 64;
  unsigned short* bsw = Bs + (wave * 32) * 64;
  int rw = (wave >> 1) * 64, cw = (wave & 1) * 64;
  int frow = lane & 15;
  int q = lane >> 4;
  int p0 = (q ^ (frow & 7)) * 8;         // half 0 chunk offset (elems)
  int p1 = ((q | 4) ^ (frow & 7)) * 8;   // half 1
  for (int k0 = 0; k0 < K; k0 += 64) {
    #pragma unroll
    for (int c = 0; c < 4; ++c) {
      GLL16(a0 + (size_t)(c * 8) * lda + k0, asw + (c * 8) * 64);
      GLL16(b0 + (size_t)(c * 8) * ldb + k0, bsw + (c * 8) * 64);
    }
    __syncthreads();
    #pragma unroll
    for (int h = 0; h < 2; ++h) {
      int p = h ? p1 : p0;
      short8 afr[4], bfr[4];
      #pragma unroll
      for (int i = 0; i < 4; ++i)
        afr[i] = *(const short8*)&As[(rw + i * 16 + frow) * 64 + p];
      #pragma unroll
      for (int j = 0; j < 4; ++j)
        bfr[j] = *(const short8*)&Bs[(cw + j * 16 + frow) * 64 + p];
      #pragma unroll
      for (int i = 0; i < 4; ++i)
        #pragma unroll
        for (int j = 0; j < 4; ++j)
          acc[i][j] = mfma16(afr[i], bfr[j], acc[i][j]);
    }
    __syncthreads();
  }
}

// ---------------------------------------------------------------------------
// 256-row 2-phase double-buffered GEMM. Block tile 256 x (JN*64), BK=64,
// 512 threads = 8 waves (2M x 4N), per-wave 128 x (JN*16), acc[8][JN].
// LDS = 2 x (256 + JN*64) x 64 bf16 (JN=4: 128 KB, JN=3: 112 KB) -> 1 blk/CU.
// Per K-step per wave: 64*JN/4... (2 halves x 8*JN MFMA) ~1240 cy/SIMD at
// JN=4 -- covers L2 staging latency intra-block (m230: 682 TF refcheck'd).
// Staging/read swizzle identical math to the proven 128 core.
// MODE 0: bf16 C.  MODE 1: fp32 relu C.
// ---------------------------------------------------------------------------
template <int MODE, int JN>
__global__ __launch_bounds__(512) void gemm256(
    const unsigned short* __restrict__ A, const unsigned short* __restrict__ B,
    void* __restrict__ Cv, int K, int CN,
    long long Abatch, long long Bbatch, long long Cbatch) {
  __shared__ unsigned short S[2 * (256 + JN * 64) * 64];
  const int BN  = JN * 64;             // block N
  const int BUF = (256 + BN) * 64;     // elems per dbuf half

  int gx = gridDim.x, gy = gridDim.y;
  int nwg = gx * gy * gridDim.z;
  int bid = blockIdx.x + gx * (blockIdx.y + gy * blockIdx.z);
  int xcd = bid & 7, idx = bid >> 3;
  int qq = nwg >> 3, rr = nwg & 7;
  int lin = (xcd < rr ? xcd * (qq + 1) : rr * (qq + 1) + (xcd - rr) * qq) + idx;
  int b = lin / (gx * gy);
  int rem = lin - b * (gx * gy);
  int by = rem / gx, bx = rem - by * gx;

  int tid = threadIdx.x, wave = tid >> 6, lane = tid & 63;
  const unsigned short* Ag = A + (size_t)b * Abatch + (size_t)by * 256 * K;
  const unsigned short* Bg = B + (size_t)b * Bbatch + (size_t)bx * BN * K;

  int sr = lane >> 3;
  int sc = ((lane & 7) ^ sr) * 8;
  const unsigned short* a0 = Ag + (size_t)(wave * 32 + sr) * K + sc;
  const unsigned short* b0 = Bg + (size_t)(wave * 32 + sr) * K + sc;  // used iff wave < 2*JN
  unsigned short* asw0 = S + wave * 32 * 64;
  unsigned short* bsw0 = S + 256 * 64 + wave * 32 * 64;
  unsigned short* asw1 = asw0 + BUF;
  unsigned short* bsw1 = bsw0 + BUF;

  int wm = wave >> 2, wn = wave & 3;
  int rw = wm * 128;
  int cw = wn * (JN * 16);
  int frow = lane & 15;
  int q = lane >> 4;
  int p0 = (q ^ (frow & 7)) * 8;
  int p1 = ((q | 4) ^ (frow & 7)) * 8;

  f32x4 zero = {0.f, 0.f, 0.f, 0.f};
  f32x4 acc[8][JN];
  #pragma unroll
  for (int i = 0; i < 8; ++i)
    #pragma unroll
    for (int j = 0; j < JN; ++j) acc[i][j] = zero;

  auto STAGE = [&](unsigned short* asw, unsigned short* bsw, int k0) {
    #pragma unroll
    for (int c = 0; c < 4; ++c)
      GLL16(a0 + (size_t)(c * 8) * K + k0, asw + (c * 8) * 64);
    if (wave < 2 * JN) {
      #pragma unroll
      for (int c = 0; c < 4; ++c)
        GLL16(b0 + (size_t)(c * 8) * K + k0, bsw + (c * 8) * 64);
    }
  };
  auto COMPUTE = [&](const unsigned short* As, const unsigned short* Bs) {
    #pragma unroll
    for (int h = 0; h < 2; ++h) {
      int p = h ? p1 : p0;
      short8 afr[8], bfr[JN];
      #pragma unroll
      for (int i = 0; i < 8; ++i)
        afr[i] = *(const short8*)&As[(rw + i * 16 + frow) * 64 + p];
      #pragma unroll
      for (int j = 0; j < JN; ++j)
        bfr[j] = *(const short8*)&Bs[(cw + j * 16 + frow) * 64 + p];
      #pragma unroll
      for (int i = 0; i < 8; ++i)
        #pragma unroll
        for (int j = 0; j < JN; ++j)
          acc[i][j] = mfma16(afr[i], bfr[j], acc[i][j]);
    }
  };

  STAGE(asw0, bsw0, 0);
  __syncthreads();
  int k0 = 0;
  for (;;) {
    if (k0 + 64 < K) STAGE(asw1, bsw1, k0 + 64);
    COMPUTE(S, S + 256 * 64);
    __syncthreads();
    k0 += 64;
    if (k0 >= K) break;
    if (k0 + 64 < K) STAGE(asw0, bsw0, k0 + 64);
    COMPUTE(S + BUF, S + BUF + 256 * 64);
    __syncthreads();
    k0 += 64;
    if (k0 >= K) break;
  }

  int cl = lane & 15;
  #pragma unroll
  for (int i = 0; i < 8; ++i)
    #pragma unroll
    for (int e = 0; e < 4; ++e) {
      size_t P = (size_t)by * 256 + rw + i * 16 + q * 4 + e;
      #pragma unroll
      for (int j = 0; j < JN; ++j) {
        size_t Q = (size_t)bx * BN + cw + j * 16 + cl;
        if (MODE == 0) {
          ((unsigned short*)Cv)[(size_t)b * Cbatch + P * CN + Q] = f2bf(acc[i][j][e]);
        } else {
          ((float*)Cv)[(size_t)b * Cbatch + P * CN + Q] = fmaxf(acc[i][j][e], 0.f);
        }
      }
    }
}

// ---------------------------------------------------------------------------
// xprep: single pass over x producing xt2[b][n][t][f] (bf16) AND
// lhsb/rhsb (bf16, K-padded to 64 with zeros) for the MFMA attention GEMM.
// ---------------------------------------------------------------------------
__global__ __launch_bounds__(256) void xprep_kernel(
    const float* __restrict__ x, const float* __restrict__ W1,
    const float* __restrict__ W2, const float* __restrict__ W3,
    unsigned short* __restrict__ xt2, unsigned short* __restrict__ lhsb,
    unsigned short* __restrict__ rhsb) {
  __shared__ float ld[4 * 1560];   // per wave: [t][f] stride 65 (pad)
  __shared__ float af[4 * 64];
  int w = threadIdx.x >> 6, lane = threadIdx.x & 63;
  size_t n = (size_t)blockIdx.x * 4 + w;
  const float* xp = x + n * Cc;
  float* lw = ld + w * 1560;
  #pragma unroll
  for (int j = 0; j < 24; ++j) {
    int i = j * 64 + lane;
    int f = i / 24, t = i - f * 24;
    lw[t * 65 + f] = xp[i];
  }
  __syncthreads();
  float a = 0.f;
  #pragma unroll
  for (int t = 0; t < Tc; ++t) a += lw[t * 65 + lane] * W1[t];
  af[w * 64 + lane] = a;
  #pragma unroll
  for (int j = 0; j < 24; ++j)
    xt2[n * Cc + j * 64 + lane] = f2bf(lw[j * 65 + lane]);
  __syncthreads();
  float l = 0.f, r = 0.f;
  if (lane < Tc) {
    #pragma unroll 8
    for (int f = 0; f < Fc; ++f) {
      l += af[w * 64 + f] * W2[f * Tc + lane];
      r += W3[f] * lw[lane * 65 + f];
    }
  }
  lhsb[n * 64 + lane] = (lane < Tc) ? f2bf(l) : (unsigned short)0;
  rhsb[n * 64 + lane] = (lane < Tc) ? f2bf(r) : (unsigned short)0;
}

// ---------------------------------------------------------------------------
// misc: Vs->bf16 (blocks 0..1023), tcat (1024..1087), bsT transpose (1088..1343)
// ---------------------------------------------------------------------------
__global__ __launch_bounds__(256) void misc_kernel(
    const float* __restrict__ Vs, const float* __restrict__ Theta,
    const float* __restrict__ bs, unsigned short* __restrict__ Vsbf,
    unsigned short* __restrict__ tcat, float* __restrict__ bsT) {
  __shared__ float t[64 * 65];
  int bid = blockIdx.x, tid = threadIdx.x;
  if (bid < 1024) {
    int i = (bid * 256 + tid) * 4;
    float4 v = *(const float4*)&Vs[i];
    ushort4 o;
    o.x = f2bf(v.x); o.y = f2bf(v.y); o.z = f2bf(v.z); o.w = f2bf(v.w);
    *(ushort4*)&Vsbf[i] = o;
  } else if (bid < 1088) {
    int i = (bid - 1024) * 256 + tid;   // 0..16383
    int m2 = i >> 6, f = i & 63;
    int k = m2 >> 6, o = m2 & 63;
    tcat[i] = (m2 < 192) ? f2bf(Theta[((size_t)k * Fc + f) * FOc + o])
                         : (unsigned short)0;
  } else {
    int id = bid - 1088;                 // 0..255: bsT[p][q] = bs[q][p]
    int p0 = (id >> 4) * 64, q0 = (id & 15) * 64;
    #pragma unroll
    for (int s = 0; s < 4; ++s) {
      int qr = (tid >> 4) + s * 16, pc = (tid & 15) * 4;
      float4 v = *(const float4*)&bs[(size_t)(q0 + qr) * Nc + p0 + pc];
      t[(pc + 0) * 65 + qr] = v.x;
      t[(pc + 1) * 65 + qr] = v.y;
      t[(pc + 2) * 65 + qr] = v.z;
      t[(pc + 3) * 65 + qr] = v.w;
    }
    __syncthreads();
    #pragma unroll
    for (int s = 0; s < 4; ++s) {
      int pr = (tid >> 4) + s * 16, qc = (tid & 15) * 4;
      float4 v = {t[pr * 65 + qc], t[pr * 65 + qc + 1],
                  t[pr * 65 + qc + 2], t[pr * 65 + qc + 3]};
      *(float4*)&bsT[(size_t)(p0 + pr) * Nc + q0 + qc] = v;
    }
  }
}

// ---------------------------------------------------------------------------
// chebT[k][m][n] = cheb[k][n][m] (fp32 transpose)
// ---------------------------------------------------------------------------
__global__ __launch_bounds__(256) void chebT_kernel(
    const float* __restrict__ cheb, float* __restrict__ chebT) {
  int k = blockIdx.z;
  int n0 = blockIdx.y * 64, m0 = blockIdx.x * 64;
  __shared__ float t[64 * 65];
  const float* src = cheb + (size_t)k * Nc * Nc;
  float* dst = chebT + (size_t)k * Nc * Nc;
  int tid = threadIdx.x;
  #pragma unroll
  for (int s = 0; s < 4; ++s) {
    int nr = (tid >> 4) + s * 16, mc = (tid & 15) * 4;
    float4 v = *(const float4*)&src[(size_t)(n0 + nr) * Nc + m0 + mc];
    t[(mc + 0) * 65 + nr] = v.x;
    t[(mc + 1) * 65 + nr] = v.y;
    t[(mc + 2) * 65 + nr] = v.z;
    t[(mc + 3) * 65 + nr] = v.w;
  }
  __syncthreads();
  #pragma unroll
  for (int s = 0; s < 4; ++s) {
    int mr = (tid >> 4) + s * 16, nc = (tid & 15) * 4;
    float4 v = {t[mr * 65 + nc], t[mr * 65 + nc + 1], t[mr * 65 + nc + 2], t[mr * 65 + nc + 3]};
    *(float4*)&dst[(size_t)(m0 + mr) * Nc + n0 + nc] = v;
  }
}

// ---------------------------------------------------------------------------
// masksoft: per (bl,m) row of ST: softmax over n (fp32), then
// Acat[bl][m][k*1024+n] = bf16(chebT[k][m][n] * softmax_n)
// ---------------------------------------------------------------------------
__global__ __launch_bounds__(256) void masksoft_kernel(
    const float* __restrict__ chebT, const unsigned short* __restrict__ ST,
    unsigned short* __restrict__ Acat, int bbase) {
  int m  = blockIdx.x & (Nc - 1);
  int bl = blockIdx.x >> 10;
  int tid = threadIdx.x;
  const unsigned short* sp = ST + ((size_t)(bbase + bl) * Nc + m) * Nc;
  ushort4 s4 = *(const ushort4*)(sp + tid * 4);
  float v0 = bf2f(s4.x), v1 = bf2f(s4.y), v2 = bf2f(s4.z), v3 = bf2f(s4.w);
  __shared__ float redm[4], reds[4];
  int wave = tid >> 6, lane = tid & 63;
  float mx = fmaxf(fmaxf(v0, v1), fmaxf(v2, v3));
  #pragma unroll
  for (int off = 32; off; off >>= 1) mx = fmaxf(mx, __shfl_xor(mx, off));
  if (lane == 0) redm[wave] = mx;
  __syncthreads();
  mx = fmaxf(fmaxf(redm[0], redm[1]), fmaxf(redm[2], redm[3]));
  float e0 = __expf(v0 - mx), e1 = __expf(v1 - mx);
  float e2 = __expf(v2 - mx), e3 = __expf(v3 - mx);
  float sm = e0 + e1 + e2 + e3;
  #pragma unroll
  for (int off = 32; off; off >>= 1) sm += __shfl_xor(sm, off);
  if (lane == 0) reds[wave] = sm;
  __syncthreads();
  float inv = 1.f / (reds[0] + reds[1] + reds[2] + reds[3]);
  e0 *= inv; e1 *= inv; e2 *= inv; e3 *= inv;
  unsigned short* ap = Acat + ((size_t)bl * Nc + m) * KKc + tid * 4;
  #pragma unroll
  for (int k = 0; k < Kc; ++k) {
    float4 c = *(const float4*)&chebT[((size_t)k * Nc + m) * Nc + tid * 4];
    ushort4 o;
    o.x = f2bf(c.x * e0); o.y = f2bf(c.y * e1);
    o.z = f2bf(c.z * e2); o.w = f2bf(c.w * e3);
    *(ushort4*)(ap + k * Nc) = o;
  }
}

// ---------------------------------------------------------------------------
// 128x128 MFMA GEMM (sigT only; K=64). MODE 2: bf16 sigmoid(C + bias[m][n]).
// XCD-aware bijective swizzle (m204).
// ---------------------------------------------------------------------------
template <int MODE>
__global__ __launch_bounds__(256) void mfma_gemm_bt(
    const unsigned short* __restrict__ A, const unsigned short* __restrict__ B,
    void* __restrict__ Cv, const float* __restrict__ bias, int K, int CN,
    long long Abatch, long long Bbatch, long long Cbatch) {
  __shared__ unsigned short As[128 * 64];
  __shared__ unsigned short Bs[128 * 64];
  int gx = gridDim.x, gy = gridDim.y;
  int nwg = gx * gy * gridDim.z;
  int bid = blockIdx.x + gx * (blockIdx.y + gy * blockIdx.z);
  int xcd = bid & 7, idx = bid >> 3;
  int qq = nwg >> 3, rr = nwg & 7;
  int lin = (xcd < rr ? xcd * (qq + 1) : rr * (qq + 1) + (xcd - rr) * qq) + idx;
  int b = lin / (gx * gy);
  int rem = lin - b * (gx * gy);
  int by = rem / gx, bx = rem - by * gx;
  int tid = threadIdx.x, wave = tid >> 6, lane = tid & 63;
  const unsigned short* Ag = A + (size_t)b * Abatch + (size_t)by * 128 * K;
  const unsigned short* Bg = B + (size_t)b * Bbatch + (size_t)bx * 128 * K;
  f32x4 zero = {0.f, 0.f, 0.f, 0.f};
  f32x4 acc[4][4];
  #pragma unroll
  for (int i = 0; i < 4; ++i)
    #pragma unroll
    for (int j = 0; j < 4; ++j) acc[i][j] = zero;
  gemm_core(Ag, Bg, K, K, K, As, Bs, wave, lane, acc);
  int rw = (wave >> 1) * 64, cw = (wave & 1) * 64;
  int q = lane >> 4, cl = lane & 15;
  #pragma unroll
  for (int i = 0; i < 4; ++i)
    #pragma unroll
    for (int e = 0; e < 4; ++e) {
      size_t P = (size_t)by * 128 + rw + i * 16 + q * 4 + e;
      #pragma unroll
      for (int j = 0; j < 4; ++j) {
        size_t Q = (size_t)bx * 128 + cw + j * 16 + cl;
        if (MODE == 0) {
          ((unsigned short*)Cv)[(size_t)b * Cbatch + P * CN + Q] = f2bf(acc[i][j][e]);
        } else if (MODE == 1) {
          ((float*)Cv)[(size_t)b * Cbatch + P * CN + Q] = fmaxf(acc[i][j][e], 0.f);
        } else {
          float v = acc[i][j][e] + bias[P * CN + Q];
          ((unsigned short*)Cv)[(size_t)b * Cbatch + P * CN + Q] =
              f2bf(1.f / (1.f + __expf(-v)));
        }
      }
    }
}

// ---------------------------------------------------------------------------
// y2 GEMM: for z=(bl,t): ycat[bl][(o*24+t)][k*1024+n] =
//   sum_f tcat[(k*64+o)][f] * xt2[bbase+bl][n][t][f].  K=64.
// ---------------------------------------------------------------------------
__global__ __launch_bounds__(256) void y2_gemm(
    const unsigned short* __restrict__ tcat, const unsigned short* __restrict__ xt2,
    unsigned short* __restrict__ ycat, int bbase) {
  __shared__ unsigned short As[128 * 64];
  __shared__ unsigned short Bs[128 * 64];
  int z = blockIdx.z;
  int bl = z / 24, t = z - bl * 24;
  int tid = threadIdx.x, wave = tid >> 6, lane = tid & 63;
  const unsigned short* Ag = tcat + (size_t)blockIdx.y * 128 * 64;
  const unsigned short* Bg = xt2 + ((size_t)(bbase + bl) * Nc + (size_t)blockIdx.x * 128) * Cc
                             + (size_t)t * 64;
  f32x4 zero = {0.f, 0.f, 0.f, 0.f};
  f32x4 acc[4][4];
  #pragma unroll
  for (int i = 0; i < 4; ++i)
    #pragma unroll
    for (int j = 0; j < 4; ++j) acc[i][j] = zero;
  gemm_core(Ag, Bg, 64, Cc, 64, As, Bs, wave, lane, acc);
  int rw = (wave >> 1) * 64, cw = (wave & 1) * 64;
  int q = lane >> 4, cl = lane & 15;
  unsigned short* yb = ycat + (size_t)bl * Cc * KKc + (size_t)t * KKc;
  #pragma unroll
  for (int i = 0; i < 4; ++i)
    #pragma unroll
    for (int e = 0; e < 4; ++e) {
      int m2 = blockIdx.y * 128 + rw + i * 16 + q * 4 + e;
      if (m2 < 192) {
        int kk = m2 >> 6, o = m2 & 63;
        unsigned short* dst = yb + (size_t)o * 24 * KKc + kk * Nc;
        #pragma unroll
        for (int j = 0; j < 4; ++j)
          dst[blockIdx.x * 128 + cw + j * 16 + cl] = f2bf(acc[i][j][e]);
      }
    }
}

// ---------------------------------------------------------------------------
extern "C" void kernel_launch(void* const* d_in, const int* in_sizes, int n_in,
                              void* d_out, int out_size, void* d_ws, size_t ws_size,
                              hipStream_t stream) {
  const float* x     = (const float*)d_in[0];
  const float* W1    = (const float*)d_in[1];
  const float* W2    = (const float*)d_in[2];
  const float* W3    = (const float*)d_in[3];
  const float* bs    = (const float*)d_in[4];
  const float* Vs    = (const float*)d_in[5];
  const float* cheb  = (const float*)d_in[6];
  const float* Theta = (const float*)d_in[7];
  float* out = (float*)d_out;

  // ws_size-adaptive: 1 pass of 16 batches (needs 348.2 MB) or 2 passes of 8
  // (needs 222.3 MB, the R4-verified layout). Deterministic per harness.
  int passes, blcount;
  if (ws_size >= 348160000ULL) { passes = 1; blcount = 16; }
  else                         { passes = 2; blcount = 8;  }

  char* w = (char*)d_ws;
  size_t Y  = (size_t)blcount * Cc * KKc * 2;   // ycat bytes
  size_t A2 = (size_t)blcount * Nc * KKc * 2;   // Acat bytes
  unsigned short* ycat = (unsigned short*)w;
  unsigned short* Acat = (unsigned short*)(w + Y);
  unsigned short* ST   = (unsigned short*)(w + Y + A2);                 // 33.55 MB
  float* chebT         = (float*)(w + Y + A2 + 33554432);               // 12.58 MB
  unsigned short* xt2  = (unsigned short*)(w + Y + A2 + 46137344);      // 50.33 MB
  unsigned short* tcat = (unsigned short*)(w + Y + A2 + 96468992);      // 32 KB
  // Front-phase temps aliased into ycat (all dead before y2 writes ycat):
  unsigned short* lhsb = (unsigned short*)w;                // 2 MB
  unsigned short* rhsb = (unsigned short*)(w + 2097152);    // 2 MB
  unsigned short* sigT = (unsigned short*)(w + 4194304);    // 33.55 MB
  float* bsT           = (float*)(w + 37748736);            // 4.19 MB
  unsigned short* Vsbf = (unsigned short*)(w + 41943040);   // 2 MB (ends 44.04 MB <= 75.5)

  xprep_kernel<<<Bc * Nc / 4, 256, 0, stream>>>(x, W1, W2, W3, xt2, lhsb, rhsb);
  misc_kernel<<<1344, 256, 0, stream>>>(Vs, Theta, bs, Vsbf, tcat, bsT);
  // sigT[p][q] = sigmoid(sum_t rhsb[p,t]*lhsb[q,t] + bsT[p][q])
  mfma_gemm_bt<2><<<dim3(8, 8, 16), 256, 0, stream>>>(
      rhsb, lhsb, sigT, bsT, 64, Nc,
      (long long)Nc * 64, (long long)Nc * 64, (long long)Nc * Nc);
  // ST[b][j][i] = sum_kk sigT[b][j][kk] * Vs[i][kk]  (256x256 tile, 2-phase)
  gemm256<0, 4><<<dim3(4, 4, 16), 512, 0, stream>>>(
      sigT, Vsbf, ST, Nc, Nc,
      (long long)Nc * Nc, 0LL, (long long)Nc * Nc);
  chebT_kernel<<<dim3(16, 16, 3), 256, 0, stream>>>(cheb, chebT);

  for (int pass = 0; pass < passes; ++pass) {
    int bbase = pass * blcount;
    masksoft_kernel<<<blcount * Nc, 256, 0, stream>>>(chebT, ST, Acat, bbase);
    y2_gemm<<<dim3(Nc / 128, 2, blcount * 24), 256, 0, stream>>>(tcat, xt2, ycat, bbase);
    // out[b][m][o*24+t] = relu( sum_{kk<3072} Acat[bl][m][kk] * ycat[bl][c''][kk] )
    // 256x192 tile -> grid 8x4xbl = 256 blocks at bl=8: exactly 1 block/CU.
    gemm256<1, 3><<<dim3(Cc / 192, Nc / 256, blcount), 512, 0, stream>>>(
        Acat, ycat, out + (size_t)bbase * Nc * Cc, KKc, Cc,
        (long long)Nc * KKc, (long long)Cc * KKc, (long long)Nc * Cc);
  }
}

// Round 7
// 564.460 us; speedup vs baseline: 1.2149x; 1.0224x over previous
//
#include <hip/hip_runtime.h>
#include <math.h>

// Problem constants: B=16, N=1024, F=64, T=24, K=3, FO=64
#define Bc 16
#define Nc 1024
#define Fc 64
#define Tc 24
#define Kc 3
#define FOc 64
#define Cc (Fc*Tc)      // 1536
#define KKc (Kc*Nc)     // 3072 = fused reduction length

typedef __attribute__((ext_vector_type(8))) short short8;   // 8 bf16 (4 VGPRs)
typedef __attribute__((ext_vector_type(4))) float f32x4;

__device__ __forceinline__ unsigned short f2bf(float f) {
  unsigned u = __float_as_uint(f);
  u += 0x7fff + ((u >> 16) & 1);   // round-to-nearest-even
  return (unsigned short)(u >> 16);
}
__device__ __forceinline__ float bf2f(unsigned short h) {
  return __uint_as_float((unsigned)h << 16);
}

#define GLL16(g, l) __builtin_amdgcn_global_load_lds( \
    (const __attribute__((address_space(1))) void*)(g), \
    (__attribute__((address_space(3))) void*)(l), 16, 0, 0)

__device__ __forceinline__ f32x4 mfma16(short8 a, short8 b, f32x4 c) {
  return __builtin_amdgcn_mfma_f32_16x16x32_bf16(a, b, c, 0, 0, 0);
}

// ---------------------------------------------------------------------------
// Single-buffer 128x128 core (sigT K=64 + y2). XOR-swizzled LDS, conflict-free.
// ---------------------------------------------------------------------------
__device__ __forceinline__ void gemm_core(
    const unsigned short* __restrict__ Ag, const unsigned short* __restrict__ Bg,
    int lda, int ldb, int K,
    unsigned short* As, unsigned short* Bs,
    int wave, int lane, f32x4 acc[4][4]) {
  int sr = lane >> 3;                    // row within a 1KB staging call
  int sc = ((lane & 7) ^ sr) * 8;        // swizzled source column (elems)
  const unsigned short* a0 = Ag + (size_t)(wave * 32 + sr) * lda + sc;
  const unsigned short* b0 = Bg + (size_t)(wave * 32 + sr) * ldb + sc;
  unsigned short* asw = As + (wave * 32) * 64;
  unsigned short* bsw = Bs + (wave * 32) * 64;
  int rw = (wave >> 1) * 64, cw = (wave & 1) * 64;
  int frow = lane & 15;
  int q = lane >> 4;
  int p0 = (q ^ (frow & 7)) * 8;         // half 0 chunk offset (elems)
  int p1 = ((q | 4) ^ (frow & 7)) * 8;   // half 1
  for (int k0 = 0; k0 < K; k0 += 64) {
    #pragma unroll
    for (int c = 0; c < 4; ++c) {
      GLL16(a0 + (size_t)(c * 8) * lda + k0, asw + (c * 8) * 64);
      GLL16(b0 + (size_t)(c * 8) * ldb + k0, bsw + (c * 8) * 64);
    }
    __syncthreads();
    #pragma unroll
    for (int h = 0; h < 2; ++h) {
      int p = h ? p1 : p0;
      short8 afr[4], bfr[4];
      #pragma unroll
      for (int i = 0; i < 4; ++i)
        afr[i] = *(const short8*)&As[(rw + i * 16 + frow) * 64 + p];
      #pragma unroll
      for (int j = 0; j < 4; ++j)
        bfr[j] = *(const short8*)&Bs[(cw + j * 16 + frow) * 64 + p];
      #pragma unroll
      for (int i = 0; i < 4; ++i)
        #pragma unroll
        for (int j = 0; j < 4; ++j)
          acc[i][j] = mfma16(afr[i], bfr[j], acc[i][j]);
    }
    __syncthreads();
  }
}

// ---------------------------------------------------------------------------
// Counted-vmcnt triple-buffered pipeline GEMM (T3+T4+T5), 128x128 tile, BK=64.
// 512 threads = 8 waves (2M x 4N); per-wave 64x32 output, acc[4][2].
// LDS = 3 x (A 16KB | B 16KB) = 96 KB -> 1 block/CU.
// Schedule per K-step t:  STAGE(t+2) ; ds_read+MFMA(t) ;
//   s_waitcnt vmcnt(4)  [retire t+1's 4 loads, keep t+2's in flight] ;
//   s_barrier.  vmem queue never drains to 0 mid-loop (m218: T3's gain IS T4).
// Safety: buffer overwritten at phase t was read at t-1 (reads complete
// before MFMA issue, before barrier); vmcnt is FIFO (m135); uniform flow.
// Requires K >= 128 (nt >= 2): call sites use K=1024, K=3072.
// MODE 0: bf16 C.  MODE 1: fp32 relu C.
// ---------------------------------------------------------------------------
template <int MODE>
__global__ __launch_bounds__(512) void gemm_pipe(
    const unsigned short* __restrict__ A, const unsigned short* __restrict__ B,
    void* __restrict__ Cv, int K, int CN,
    long long Abatch, long long Bbatch, long long Cbatch) {
  __shared__ unsigned short S[6 * 128 * 64];   // 96 KB: A0|B0|A1|B1|A2|B2
  int gx = gridDim.x, gy = gridDim.y;
  int nwg = gx * gy * gridDim.z;
  int bid = blockIdx.x + gx * (blockIdx.y + gy * blockIdx.z);
  int xcd = bid & 7, idx = bid >> 3;
  int qq = nwg >> 3, rr = nwg & 7;
  int lin = (xcd < rr ? xcd * (qq + 1) : rr * (qq + 1) + (xcd - rr) * qq) + idx;
  int b = lin / (gx * gy);
  int rem = lin - b * (gx * gy);
  int by = rem / gx, bx = rem - by * gx;

  int tid = threadIdx.x, wave = tid >> 6, lane = tid & 63;
  const unsigned short* Ag = A + (size_t)b * Abatch + (size_t)by * 128 * K;
  const unsigned short* Bg = B + (size_t)b * Bbatch + (size_t)bx * 128 * K;

  // staging addresses (same swizzle invariant as gemm_core: row%8 == sr)
  int sr = lane >> 3;
  int sc = ((lane & 7) ^ sr) * 8;
  const unsigned short* a0 = Ag + (size_t)(wave * 16 + sr) * K + sc;
  const unsigned short* b0 = Bg + (size_t)(wave * 16 + sr) * K + sc;
  int soff = wave * 16 * 64;

  unsigned short* A0 = S;
  unsigned short* B0 = S + 128 * 64;
  unsigned short* A1 = S + 2 * 128 * 64;
  unsigned short* B1 = S + 3 * 128 * 64;
  unsigned short* A2 = S + 4 * 128 * 64;
  unsigned short* B2 = S + 5 * 128 * 64;

  int wm = wave >> 2, wn = wave & 3;
  int rw = wm * 64, cw = wn * 32;
  int frow = lane & 15;
  int q = lane >> 4;
  int p0 = (q ^ (frow & 7)) * 8;
  int p1 = ((q | 4) ^ (frow & 7)) * 8;

  f32x4 zero = {0.f, 0.f, 0.f, 0.f};
  f32x4 acc[4][2];
  #pragma unroll
  for (int i = 0; i < 4; ++i)
    #pragma unroll
    for (int j = 0; j < 2; ++j) acc[i][j] = zero;

  // per wave: 2 A-loads + 2 B-loads (rows wave*16 .. wave*16+15)
  auto STAGE = [&](unsigned short* Ab, unsigned short* Bb, int k0) {
    GLL16(a0 + k0, Ab + soff);
    GLL16(a0 + (size_t)8 * K + k0, Ab + soff + 8 * 64);
    GLL16(b0 + k0, Bb + soff);
    GLL16(b0 + (size_t)8 * K + k0, Bb + soff + 8 * 64);
  };
  auto COMPUTE = [&](const unsigned short* As_, const unsigned short* Bs_) {
    #pragma unroll
    for (int h = 0; h < 2; ++h) {
      int p = h ? p1 : p0;
      short8 afr[4], bfr[2];
      #pragma unroll
      for (int i = 0; i < 4; ++i)
        afr[i] = *(const short8*)&As_[(rw + i * 16 + frow) * 64 + p];
      #pragma unroll
      for (int j = 0; j < 2; ++j)
        bfr[j] = *(const short8*)&Bs_[(cw + j * 16 + frow) * 64 + p];
      __builtin_amdgcn_s_setprio(1);
      #pragma unroll
      for (int i = 0; i < 4; ++i)
        #pragma unroll
        for (int j = 0; j < 2; ++j)
          acc[i][j] = mfma16(afr[i], bfr[j], acc[i][j]);
      __builtin_amdgcn_s_setprio(0);
    }
  };

  int nt = K >> 6;   // >= 2 at all call sites
  STAGE(A0, B0, 0);
  STAGE(A1, B1, 64);
  asm volatile("s_waitcnt vmcnt(4)" ::: "memory");   // tile 0 landed
  __builtin_amdgcn_sched_barrier(0);
  __builtin_amdgcn_s_barrier();

  unsigned short *cA = A0, *cB = B0;   // current (tile t)
  unsigned short *nA = A1, *nB = B1;   // next (tile t+1)
  unsigned short *fA = A2, *fB = B2;   // free (being filled with t+2)
  for (int t = 0; t < nt; ++t) {
    if (t + 2 < nt) STAGE(fA, fB, (t + 2) << 6);
    COMPUTE(cA, cB);
    if (t + 1 < nt) {
      if (t + 2 < nt) {
        asm volatile("s_waitcnt vmcnt(4)" ::: "memory");  // t+1 landed; t+2 in flight
      } else {
        asm volatile("s_waitcnt vmcnt(0)" ::: "memory");  // last prefetch: full drain
      }
      __builtin_amdgcn_sched_barrier(0);
      __builtin_amdgcn_s_barrier();
    }
    unsigned short* tA = cA; cA = nA; nA = fA; fA = tA;
    unsigned short* tB = cB; cB = nB; nB = fB; fB = tB;
  }

  int cl = lane & 15;
  #pragma unroll
  for (int i = 0; i < 4; ++i)
    #pragma unroll
    for (int e = 0; e < 4; ++e) {
      size_t P = (size_t)by * 128 + rw + i * 16 + q * 4 + e;
      #pragma unroll
      for (int j = 0; j < 2; ++j) {
        size_t Q = (size_t)bx * 128 + cw + j * 16 + cl;
        if (MODE == 0) {
          ((unsigned short*)Cv)[(size_t)b * Cbatch + P * CN + Q] = f2bf(acc[i][j][e]);
        } else {
          ((float*)Cv)[(size_t)b * Cbatch + P * CN + Q] = fmaxf(acc[i][j][e], 0.f);
        }
      }
    }
}

// ---------------------------------------------------------------------------
// xprep: single pass over x producing xt2[b][n][t][f] (bf16) AND
// lhsb/rhsb (bf16, K-padded to 64 with zeros) for the MFMA attention GEMM.
// ---------------------------------------------------------------------------
__global__ __launch_bounds__(256) void xprep_kernel(
    const float* __restrict__ x, const float* __restrict__ W1,
    const float* __restrict__ W2, const float* __restrict__ W3,
    unsigned short* __restrict__ xt2, unsigned short* __restrict__ lhsb,
    unsigned short* __restrict__ rhsb) {
  __shared__ float ld[4 * 1560];   // per wave: [t][f] stride 65 (pad)
  __shared__ float af[4 * 64];
  int w = threadIdx.x >> 6, lane = threadIdx.x & 63;
  size_t n = (size_t)blockIdx.x * 4 + w;
  const float* xp = x + n * Cc;
  float* lw = ld + w * 1560;
  #pragma unroll
  for (int j = 0; j < 24; ++j) {
    int i = j * 64 + lane;
    int f = i / 24, t = i - f * 24;
    lw[t * 65 + f] = xp[i];
  }
  __syncthreads();
  float a = 0.f;
  #pragma unroll
  for (int t = 0; t < Tc; ++t) a += lw[t * 65 + lane] * W1[t];
  af[w * 64 + lane] = a;
  #pragma unroll
  for (int j = 0; j < 24; ++j)
    xt2[n * Cc + j * 64 + lane] = f2bf(lw[j * 65 + lane]);
  __syncthreads();
  float l = 0.f, r = 0.f;
  if (lane < Tc) {
    #pragma unroll 8
    for (int f = 0; f < Fc; ++f) {
      l += af[w * 64 + f] * W2[f * Tc + lane];
      r += W3[f] * lw[lane * 65 + f];
    }
  }
  lhsb[n * 64 + lane] = (lane < Tc) ? f2bf(l) : (unsigned short)0;
  rhsb[n * 64 + lane] = (lane < Tc) ? f2bf(r) : (unsigned short)0;
}

// ---------------------------------------------------------------------------
// misc: Vs->bf16 (blocks 0..1023), tcat (1024..1087), bsT transpose (1088..1343)
// ---------------------------------------------------------------------------
__global__ __launch_bounds__(256) void misc_kernel(
    const float* __restrict__ Vs, const float* __restrict__ Theta,
    const float* __restrict__ bs, unsigned short* __restrict__ Vsbf,
    unsigned short* __restrict__ tcat, float* __restrict__ bsT) {
  __shared__ float t[64 * 65];
  int bid = blockIdx.x, tid = threadIdx.x;
  if (bid < 1024) {
    int i = (bid * 256 + tid) * 4;
    float4 v = *(const float4*)&Vs[i];
    ushort4 o;
    o.x = f2bf(v.x); o.y = f2bf(v.y); o.z = f2bf(v.z); o.w = f2bf(v.w);
    *(ushort4*)&Vsbf[i] = o;
  } else if (bid < 1088) {
    int i = (bid - 1024) * 256 + tid;   // 0..16383
    int m2 = i >> 6, f = i & 63;
    int k = m2 >> 6, o = m2 & 63;
    tcat[i] = (m2 < 192) ? f2bf(Theta[((size_t)k * Fc + f) * FOc + o])
                         : (unsigned short)0;
  } else {
    int id = bid - 1088;                 // 0..255: bsT[p][q] = bs[q][p]
    int p0 = (id >> 4) * 64, q0 = (id & 15) * 64;
    #pragma unroll
    for (int s = 0; s < 4; ++s) {
      int qr = (tid >> 4) + s * 16, pc = (tid & 15) * 4;
      float4 v = *(const float4*)&bs[(size_t)(q0 + qr) * Nc + p0 + pc];
      t[(pc + 0) * 65 + qr] = v.x;
      t[(pc + 1) * 65 + qr] = v.y;
      t[(pc + 2) * 65 + qr] = v.z;
      t[(pc + 3) * 65 + qr] = v.w;
    }
    __syncthreads();
    #pragma unroll
    for (int s = 0; s < 4; ++s) {
      int pr = (tid >> 4) + s * 16, qc = (tid & 15) * 4;
      float4 v = {t[pr * 65 + qc], t[pr * 65 + qc + 1],
                  t[pr * 65 + qc + 2], t[pr * 65 + qc + 3]};
      *(float4*)&bsT[(size_t)(p0 + pr) * Nc + q0 + qc] = v;
    }
  }
}

// ---------------------------------------------------------------------------
// chebT[k][m][n] = cheb[k][n][m] (fp32 transpose)
// ---------------------------------------------------------------------------
__global__ __launch_bounds__(256) void chebT_kernel(
    const float* __restrict__ cheb, float* __restrict__ chebT) {
  int k = blockIdx.z;
  int n0 = blockIdx.y * 64, m0 = blockIdx.x * 64;
  __shared__ float t[64 * 65];
  const float* src = cheb + (size_t)k * Nc * Nc;
  float* dst = chebT + (size_t)k * Nc * Nc;
  int tid = threadIdx.x;
  #pragma unroll
  for (int s = 0; s < 4; ++s) {
    int nr = (tid >> 4) + s * 16, mc = (tid & 15) * 4;
    float4 v = *(const float4*)&src[(size_t)(n0 + nr) * Nc + m0 + mc];
    t[(mc + 0) * 65 + nr] = v.x;
    t[(mc + 1) * 65 + nr] = v.y;
    t[(mc + 2) * 65 + nr] = v.z;
    t[(mc + 3) * 65 + nr] = v.w;
  }
  __syncthreads();
  #pragma unroll
  for (int s = 0; s < 4; ++s) {
    int mr = (tid >> 4) + s * 16, nc = (tid & 15) * 4;
    float4 v = {t[mr * 65 + nc], t[mr * 65 + nc + 1], t[mr * 65 + nc + 2], t[mr * 65 + nc + 3]};
    *(float4*)&dst[(size_t)(m0 + mr) * Nc + n0 + nc] = v;
  }
}

// ---------------------------------------------------------------------------
// masksoft: per (bl,m) row of ST: softmax over n (fp32), then
// Acat[bl][m][k*1024+n] = bf16(chebT[k][m][n] * softmax_n)
// ---------------------------------------------------------------------------
__global__ __launch_bounds__(256) void masksoft_kernel(
    const float* __restrict__ chebT, const unsigned short* __restrict__ ST,
    unsigned short* __restrict__ Acat, int bbase) {
  int m  = blockIdx.x & (Nc - 1);
  int bl = blockIdx.x >> 10;
  int tid = threadIdx.x;
  const unsigned short* sp = ST + ((size_t)(bbase + bl) * Nc + m) * Nc;
  ushort4 s4 = *(const ushort4*)(sp + tid * 4);
  float v0 = bf2f(s4.x), v1 = bf2f(s4.y), v2 = bf2f(s4.z), v3 = bf2f(s4.w);
  __shared__ float redm[4], reds[4];
  int wave = tid >> 6, lane = tid & 63;
  float mx = fmaxf(fmaxf(v0, v1), fmaxf(v2, v3));
  #pragma unroll
  for (int off = 32; off; off >>= 1) mx = fmaxf(mx, __shfl_xor(mx, off));
  if (lane == 0) redm[wave] = mx;
  __syncthreads();
  mx = fmaxf(fmaxf(redm[0], redm[1]), fmaxf(redm[2], redm[3]));
  float e0 = __expf(v0 - mx), e1 = __expf(v1 - mx);
  float e2 = __expf(v2 - mx), e3 = __expf(v3 - mx);
  float sm = e0 + e1 + e2 + e3;
  #pragma unroll
  for (int off = 32; off; off >>= 1) sm += __shfl_xor(sm, off);
  if (lane == 0) reds[wave] = sm;
  __syncthreads();
  float inv = 1.f / (reds[0] + reds[1] + reds[2] + reds[3]);
  e0 *= inv; e1 *= inv; e2 *= inv; e3 *= inv;
  unsigned short* ap = Acat + ((size_t)bl * Nc + m) * KKc + tid * 4;
  #pragma unroll
  for (int k = 0; k < Kc; ++k) {
    float4 c = *(const float4*)&chebT[((size_t)k * Nc + m) * Nc + tid * 4];
    ushort4 o;
    o.x = f2bf(c.x * e0); o.y = f2bf(c.y * e1);
    o.z = f2bf(c.z * e2); o.w = f2bf(c.w * e3);
    *(ushort4*)(ap + k * Nc) = o;
  }
}

// ---------------------------------------------------------------------------
// 128x128 MFMA GEMM (sigT only; K=64). MODE 2: bf16 sigmoid(C + bias[m][n]).
// XCD-aware bijective swizzle (m204).
// ---------------------------------------------------------------------------
template <int MODE>
__global__ __launch_bounds__(256) void mfma_gemm_bt(
    const unsigned short* __restrict__ A, const unsigned short* __restrict__ B,
    void* __restrict__ Cv, const float* __restrict__ bias, int K, int CN,
    long long Abatch, long long Bbatch, long long Cbatch) {
  __shared__ unsigned short As[128 * 64];
  __shared__ unsigned short Bs[128 * 64];
  int gx = gridDim.x, gy = gridDim.y;
  int nwg = gx * gy * gridDim.z;
  int bid = blockIdx.x + gx * (blockIdx.y + gy * blockIdx.z);
  int xcd = bid & 7, idx = bid >> 3;
  int qq = nwg >> 3, rr = nwg & 7;
  int lin = (xcd < rr ? xcd * (qq + 1) : rr * (qq + 1) + (xcd - rr) * qq) + idx;
  int b = lin / (gx * gy);
  int rem = lin - b * (gx * gy);
  int by = rem / gx, bx = rem - by * gx;
  int tid = threadIdx.x, wave = tid >> 6, lane = tid & 63;
  const unsigned short* Ag = A + (size_t)b * Abatch + (size_t)by * 128 * K;
  const unsigned short* Bg = B + (size_t)b * Bbatch + (size_t)bx * 128 * K;
  f32x4 zero = {0.f, 0.f, 0.f, 0.f};
  f32x4 acc[4][4];
  #pragma unroll
  for (int i = 0; i < 4; ++i)
    #pragma unroll
    for (int j = 0; j < 4; ++j) acc[i][j] = zero;
  gemm_core(Ag, Bg, K, K, K, As, Bs, wave, lane, acc);
  int rw = (wave >> 1) * 64, cw = (wave & 1) * 64;
  int q = lane >> 4, cl = lane & 15;
  #pragma unroll
  for (int i = 0; i < 4; ++i)
    #pragma unroll
    for (int e = 0; e < 4; ++e) {
      size_t P = (size_t)by * 128 + rw + i * 16 + q * 4 + e;
      #pragma unroll
      for (int j = 0; j < 4; ++j) {
        size_t Q = (size_t)bx * 128 + cw + j * 16 + cl;
        if (MODE == 0) {
          ((unsigned short*)Cv)[(size_t)b * Cbatch + P * CN + Q] = f2bf(acc[i][j][e]);
        } else if (MODE == 1) {
          ((float*)Cv)[(size_t)b * Cbatch + P * CN + Q] = fmaxf(acc[i][j][e], 0.f);
        } else {
          float v = acc[i][j][e] + bias[P * CN + Q];
          ((unsigned short*)Cv)[(size_t)b * Cbatch + P * CN + Q] =
              f2bf(1.f / (1.f + __expf(-v)));
        }
      }
    }
}

// ---------------------------------------------------------------------------
// y2 GEMM: for z=(bl,t): ycat[bl][(o*24+t)][k*1024+n] =
//   sum_f tcat[(k*64+o)][f] * xt2[bbase+bl][n][t][f].  K=64.
// ---------------------------------------------------------------------------
__global__ __launch_bounds__(256) void y2_gemm(
    const unsigned short* __restrict__ tcat, const unsigned short* __restrict__ xt2,
    unsigned short* __restrict__ ycat, int bbase) {
  __shared__ unsigned short As[128 * 64];
  __shared__ unsigned short Bs[128 * 64];
  int z = blockIdx.z;
  int bl = z / 24, t = z - bl * 24;
  int tid = threadIdx.x, wave = tid >> 6, lane = tid & 63;
  const unsigned short* Ag = tcat + (size_t)blockIdx.y * 128 * 64;
  const unsigned short* Bg = xt2 + ((size_t)(bbase + bl) * Nc + (size_t)blockIdx.x * 128) * Cc
                             + (size_t)t * 64;
  f32x4 zero = {0.f, 0.f, 0.f, 0.f};
  f32x4 acc[4][4];
  #pragma unroll
  for (int i = 0; i < 4; ++i)
    #pragma unroll
    for (int j = 0; j < 4; ++j) acc[i][j] = zero;
  gemm_core(Ag, Bg, 64, Cc, 64, As, Bs, wave, lane, acc);
  int rw = (wave >> 1) * 64, cw = (wave & 1) * 64;
  int q = lane >> 4, cl = lane & 15;
  unsigned short* yb = ycat + (size_t)bl * Cc * KKc + (size_t)t * KKc;
  #pragma unroll
  for (int i = 0; i < 4; ++i)
    #pragma unroll
    for (int e = 0; e < 4; ++e) {
      int m2 = blockIdx.y * 128 + rw + i * 16 + q * 4 + e;
      if (m2 < 192) {
        int kk = m2 >> 6, o = m2 & 63;
        unsigned short* dst = yb + (size_t)o * 24 * KKc + kk * Nc;
        #pragma unroll
        for (int j = 0; j < 4; ++j)
          dst[blockIdx.x * 128 + cw + j * 16 + cl] = f2bf(acc[i][j][e]);
      }
    }
}

// ---------------------------------------------------------------------------
extern "C" void kernel_launch(void* const* d_in, const int* in_sizes, int n_in,
                              void* d_out, int out_size, void* d_ws, size_t ws_size,
                              hipStream_t stream) {
  const float* x     = (const float*)d_in[0];
  const float* W1    = (const float*)d_in[1];
  const float* W2    = (const float*)d_in[2];
  const float* W3    = (const float*)d_in[3];
  const float* bs    = (const float*)d_in[4];
  const float* Vs    = (const float*)d_in[5];
  const float* cheb  = (const float*)d_in[6];
  const float* Theta = (const float*)d_in[7];
  float* out = (float*)d_out;

  // ws_size-adaptive: 1 pass of 16 batches (needs 348.2 MB) or 2 passes of 8
  // (needs 222.3 MB, the R4-verified layout). Deterministic per harness.
  int passes, blcount;
  if (ws_size >= 348160000ULL) { passes = 1; blcount = 16; }
  else                         { passes = 2; blcount = 8;  }

  char* w = (char*)d_ws;
  size_t Y  = (size_t)blcount * Cc * KKc * 2;   // ycat bytes
  size_t A2 = (size_t)blcount * Nc * KKc * 2;   // Acat bytes
  unsigned short* ycat = (unsigned short*)w;
  unsigned short* Acat = (unsigned short*)(w + Y);
  unsigned short* ST   = (unsigned short*)(w + Y + A2);                 // 33.55 MB
  float* chebT         = (float*)(w + Y + A2 + 33554432);               // 12.58 MB
  unsigned short* xt2  = (unsigned short*)(w + Y + A2 + 46137344);      // 50.33 MB
  unsigned short* tcat = (unsigned short*)(w + Y + A2 + 96468992);      // 32 KB
  // Front-phase temps aliased into ycat (all dead before y2 writes ycat):
  unsigned short* lhsb = (unsigned short*)w;                // 2 MB
  unsigned short* rhsb = (unsigned short*)(w + 2097152);    // 2 MB
  unsigned short* sigT = (unsigned short*)(w + 4194304);    // 33.55 MB
  float* bsT           = (float*)(w + 37748736);            // 4.19 MB
  unsigned short* Vsbf = (unsigned short*)(w + 41943040);   // 2 MB (ends 44.04 MB <= 75.5)

  xprep_kernel<<<Bc * Nc / 4, 256, 0, stream>>>(x, W1, W2, W3, xt2, lhsb, rhsb);
  misc_kernel<<<1344, 256, 0, stream>>>(Vs, Theta, bs, Vsbf, tcat, bsT);
  // sigT[p][q] = sigmoid(sum_t rhsb[p,t]*lhsb[q,t] + bsT[p][q])  (K=64, old core)
  mfma_gemm_bt<2><<<dim3(8, 8, 16), 256, 0, stream>>>(
      rhsb, lhsb, sigT, bsT, 64, Nc,
      (long long)Nc * 64, (long long)Nc * 64, (long long)Nc * Nc);
  // ST[b][j][i] = sum_kk sigT[b][j][kk] * Vs[i][kk]  (counted-vmcnt pipeline)
  gemm_pipe<0><<<dim3(8, 8, 16), 512, 0, stream>>>(
      sigT, Vsbf, ST, Nc, Nc,
      (long long)Nc * Nc, 0LL, (long long)Nc * Nc);
  chebT_kernel<<<dim3(16, 16, 3), 256, 0, stream>>>(cheb, chebT);

  for (int pass = 0; pass < passes; ++pass) {
    int bbase = pass * blcount;
    masksoft_kernel<<<blcount * Nc, 256, 0, stream>>>(chebT, ST, Acat, bbase);
    y2_gemm<<<dim3(Nc / 128, 2, blcount * 24), 256, 0, stream>>>(tcat, xt2, ycat, bbase);
    // out[b][m][o*24+t] = relu( sum_{kk<3072} Acat[bl][m][kk] * ycat[bl][c''][kk] )
    gemm_pipe<1><<<dim3(Cc / 128, Nc / 128, blcount), 512, 0, stream>>>(
        Acat, ycat, out + (size_t)bbase * Nc * Cc, KKc, Cc,
        (long long)Nc * KKc, (long long)Cc * KKc, (long long)Nc * Cc);
  }
}

// Round 8
// 547.392 us; speedup vs baseline: 1.2528x; 1.0312x over previous
//
#include <hip/hip_runtime.h>
#include <math.h>

// Problem constants: B=16, N=1024, F=64, T=24, K=3, FO=64
#define Bc 16
#define Nc 1024
#define Fc 64
#define Tc 24
#define Kc 3
#define FOc 64
#define Cc (Fc*Tc)      // 1536
#define KKc (Kc*Nc)     // 3072 = fused reduction length

typedef __attribute__((ext_vector_type(8))) short short8;   // 8 bf16 (4 VGPRs)
typedef __attribute__((ext_vector_type(8))) unsigned short u16x8;
typedef __attribute__((ext_vector_type(4))) float f32x4;

__device__ __forceinline__ unsigned short f2bf(float f) {
  unsigned u = __float_as_uint(f);
  u += 0x7fff + ((u >> 16) & 1);   // round-to-nearest-even
  return (unsigned short)(u >> 16);
}
__device__ __forceinline__ float bf2f(unsigned short h) {
  return __uint_as_float((unsigned)h << 16);
}

#define GLL16(g, l) __builtin_amdgcn_global_load_lds( \
    (const __attribute__((address_space(1))) void*)(g), \
    (__attribute__((address_space(3))) void*)(l), 16, 0, 0)

__device__ __forceinline__ f32x4 mfma16(short8 a, short8 b, f32x4 c) {
  return __builtin_amdgcn_mfma_f32_16x16x32_bf16(a, b, c, 0, 0, 0);
}

// ---------------------------------------------------------------------------
// GEMM core: 128x128 tile, BK=64, XOR-swizzled LDS (conflict-free, R4-verified).
// 2-barrier structure at 3 blocks/CU: FETCH at compulsory floor (batch fully
// resident per XCD), inter-block TLP hides staging latency. Empirically the
// optimum of the reachable family (R3/R4/R5/R7 structural variants: 233-356us
// vs 213us here; see session journal).
// ---------------------------------------------------------------------------
__device__ __forceinline__ void gemm_core(
    const unsigned short* __restrict__ Ag, const unsigned short* __restrict__ Bg,
    int lda, int ldb, int K,
    unsigned short* As, unsigned short* Bs,
    int wave, int lane, f32x4 acc[4][4]) {
  int sr = lane >> 3;                    // row within a 1KB staging call
  int sc = ((lane & 7) ^ sr) * 8;        // swizzled source column (elems)
  const unsigned short* a0 = Ag + (size_t)(wave * 32 + sr) * lda + sc;
  const unsigned short* b0 = Bg + (size_t)(wave * 32 + sr) * ldb + sc;
  unsigned short* asw = As + (wave * 32) * 64;
  unsigned short* bsw = Bs + (wave * 32) * 64;
  int rw = (wave >> 1) * 64, cw = (wave & 1) * 64;
  int frow = lane & 15;
  int q = lane >> 4;
  int p0 = (q ^ (frow & 7)) * 8;         // half 0 chunk offset (elems)
  int p1 = ((q | 4) ^ (frow & 7)) * 8;   // half 1
  for (int k0 = 0; k0 < K; k0 += 64) {
    #pragma unroll
    for (int c = 0; c < 4; ++c) {
      GLL16(a0 + (size_t)(c * 8) * lda + k0, asw + (c * 8) * 64);
      GLL16(b0 + (size_t)(c * 8) * ldb + k0, bsw + (c * 8) * 64);
    }
    __syncthreads();
    #pragma unroll
    for (int h = 0; h < 2; ++h) {
      int p = h ? p1 : p0;
      short8 afr[4], bfr[4];
      #pragma unroll
      for (int i = 0; i < 4; ++i)
        afr[i] = *(const short8*)&As[(rw + i * 16 + frow) * 64 + p];
      #pragma unroll
      for (int j = 0; j < 4; ++j)
        bfr[j] = *(const short8*)&Bs[(cw + j * 16 + frow) * 64 + p];
      #pragma unroll
      for (int i = 0; i < 4; ++i)
        #pragma unroll
        for (int j = 0; j < 4; ++j)
          acc[i][j] = mfma16(afr[i], bfr[j], acc[i][j]);
    }
    __syncthreads();
  }
}

// ---------------------------------------------------------------------------
// xprep: single pass over x producing xt2[b][n][t][f] (bf16) AND
// lhsb/rhsb (bf16, K-padded to 64 with zeros) for the MFMA attention GEMM.
// ---------------------------------------------------------------------------
__global__ __launch_bounds__(256) void xprep_kernel(
    const float* __restrict__ x, const float* __restrict__ W1,
    const float* __restrict__ W2, const float* __restrict__ W3,
    unsigned short* __restrict__ xt2, unsigned short* __restrict__ lhsb,
    unsigned short* __restrict__ rhsb) {
  __shared__ float ld[4 * 1560];   // per wave: [t][f] stride 65 (pad)
  __shared__ float af[4 * 64];
  int w = threadIdx.x >> 6, lane = threadIdx.x & 63;
  size_t n = (size_t)blockIdx.x * 4 + w;
  const float* xp = x + n * Cc;
  float* lw = ld + w * 1560;
  #pragma unroll
  for (int j = 0; j < 24; ++j) {
    int i = j * 64 + lane;
    int f = i / 24, t = i - f * 24;
    lw[t * 65 + f] = xp[i];
  }
  __syncthreads();
  float a = 0.f;
  #pragma unroll
  for (int t = 0; t < Tc; ++t) a += lw[t * 65 + lane] * W1[t];
  af[w * 64 + lane] = a;
  #pragma unroll
  for (int j = 0; j < 24; ++j)
    xt2[n * Cc + j * 64 + lane] = f2bf(lw[j * 65 + lane]);
  __syncthreads();
  float l = 0.f, r = 0.f;
  if (lane < Tc) {
    #pragma unroll 8
    for (int f = 0; f < Fc; ++f) {
      l += af[w * 64 + f] * W2[f * Tc + lane];
      r += W3[f] * lw[lane * 65 + f];
    }
  }
  lhsb[n * 64 + lane] = (lane < Tc) ? f2bf(l) : (unsigned short)0;
  rhsb[n * 64 + lane] = (lane < Tc) ? f2bf(r) : (unsigned short)0;
}

// ---------------------------------------------------------------------------
// misc: Vs->bf16 (blocks 0..1023), tcat (1024..1087), bsT transpose (1088..1343)
// ---------------------------------------------------------------------------
__global__ __launch_bounds__(256) void misc_kernel(
    const float* __restrict__ Vs, const float* __restrict__ Theta,
    const float* __restrict__ bs, unsigned short* __restrict__ Vsbf,
    unsigned short* __restrict__ tcat, float* __restrict__ bsT) {
  __shared__ float t[64 * 65];
  int bid = blockIdx.x, tid = threadIdx.x;
  if (bid < 1024) {
    int i = (bid * 256 + tid) * 4;
    float4 v = *(const float4*)&Vs[i];
    ushort4 o;
    o.x = f2bf(v.x); o.y = f2bf(v.y); o.z = f2bf(v.z); o.w = f2bf(v.w);
    *(ushort4*)&Vsbf[i] = o;
  } else if (bid < 1088) {
    int i = (bid - 1024) * 256 + tid;   // 0..16383
    int m2 = i >> 6, f = i & 63;
    int k = m2 >> 6, o = m2 & 63;
    tcat[i] = (m2 < 192) ? f2bf(Theta[((size_t)k * Fc + f) * FOc + o])
                         : (unsigned short)0;
  } else {
    int id = bid - 1088;                 // 0..255: bsT[p][q] = bs[q][p]
    int p0 = (id >> 4) * 64, q0 = (id & 15) * 64;
    #pragma unroll
    for (int s = 0; s < 4; ++s) {
      int qr = (tid >> 4) + s * 16, pc = (tid & 15) * 4;
      float4 v = *(const float4*)&bs[(size_t)(q0 + qr) * Nc + p0 + pc];
      t[(pc + 0) * 65 + qr] = v.x;
      t[(pc + 1) * 65 + qr] = v.y;
      t[(pc + 2) * 65 + qr] = v.z;
      t[(pc + 3) * 65 + qr] = v.w;
    }
    __syncthreads();
    #pragma unroll
    for (int s = 0; s < 4; ++s) {
      int pr = (tid >> 4) + s * 16, qc = (tid & 15) * 4;
      float4 v = {t[pr * 65 + qc], t[pr * 65 + qc + 1],
                  t[pr * 65 + qc + 2], t[pr * 65 + qc + 3]};
      *(float4*)&bsT[(size_t)(p0 + pr) * Nc + q0 + qc] = v;
    }
  }
}

// ---------------------------------------------------------------------------
// chebT[k][m][n] = cheb[k][n][m] (fp32 transpose)
// ---------------------------------------------------------------------------
__global__ __launch_bounds__(256) void chebT_kernel(
    const float* __restrict__ cheb, float* __restrict__ chebT) {
  int k = blockIdx.z;
  int n0 = blockIdx.y * 64, m0 = blockIdx.x * 64;
  __shared__ float t[64 * 65];
  const float* src = cheb + (size_t)k * Nc * Nc;
  float* dst = chebT + (size_t)k * Nc * Nc;
  int tid = threadIdx.x;
  #pragma unroll
  for (int s = 0; s < 4; ++s) {
    int nr = (tid >> 4) + s * 16, mc = (tid & 15) * 4;
    float4 v = *(const float4*)&src[(size_t)(n0 + nr) * Nc + m0 + mc];
    t[(mc + 0) * 65 + nr] = v.x;
    t[(mc + 1) * 65 + nr] = v.y;
    t[(mc + 2) * 65 + nr] = v.z;
    t[(mc + 3) * 65 + nr] = v.w;
  }
  __syncthreads();
  #pragma unroll
  for (int s = 0; s < 4; ++s) {
    int mr = (tid >> 4) + s * 16, nc = (tid & 15) * 4;
    float4 v = {t[mr * 65 + nc], t[mr * 65 + nc + 1], t[mr * 65 + nc + 2], t[mr * 65 + nc + 3]};
    *(float4*)&dst[(size_t)(m0 + mr) * Nc + n0 + nc] = v;
  }
}

// ---------------------------------------------------------------------------
// masksoft: per (bl,m) row of ST: softmax over n (fp32), then
// Acat[bl][m][k*1024+n] = bf16(chebT[k][m][n] * softmax_n)
// ---------------------------------------------------------------------------
__global__ __launch_bounds__(256) void masksoft_kernel(
    const float* __restrict__ chebT, const unsigned short* __restrict__ ST,
    unsigned short* __restrict__ Acat, int bbase) {
  int m  = blockIdx.x & (Nc - 1);
  int bl = blockIdx.x >> 10;
  int tid = threadIdx.x;
  const unsigned short* sp = ST + ((size_t)(bbase + bl) * Nc + m) * Nc;
  ushort4 s4 = *(const ushort4*)(sp + tid * 4);
  float v0 = bf2f(s4.x), v1 = bf2f(s4.y), v2 = bf2f(s4.z), v3 = bf2f(s4.w);
  __shared__ float redm[4], reds[4];
  int wave = tid >> 6, lane = tid & 63;
  float mx = fmaxf(fmaxf(v0, v1), fmaxf(v2, v3));
  #pragma unroll
  for (int off = 32; off; off >>= 1) mx = fmaxf(mx, __shfl_xor(mx, off));
  if (lane == 0) redm[wave] = mx;
  __syncthreads();
  mx = fmaxf(fmaxf(redm[0], redm[1]), fmaxf(redm[2], redm[3]));
  float e0 = __expf(v0 - mx), e1 = __expf(v1 - mx);
  float e2 = __expf(v2 - mx), e3 = __expf(v3 - mx);
  float sm = e0 + e1 + e2 + e3;
  #pragma unroll
  for (int off = 32; off; off >>= 1) sm += __shfl_xor(sm, off);
  if (lane == 0) reds[wave] = sm;
  __syncthreads();
  float inv = 1.f / (reds[0] + reds[1] + reds[2] + reds[3]);
  e0 *= inv; e1 *= inv; e2 *= inv; e3 *= inv;
  unsigned short* ap = Acat + ((size_t)bl * Nc + m) * KKc + tid * 4;
  #pragma unroll
  for (int k = 0; k < Kc; ++k) {
    float4 c = *(const float4*)&chebT[((size_t)k * Nc + m) * Nc + tid * 4];
    ushort4 o;
    o.x = f2bf(c.x * e0); o.y = f2bf(c.y * e1);
    o.z = f2bf(c.z * e2); o.w = f2bf(c.w * e3);
    *(ushort4*)(ap + k * Nc) = o;
  }
}

// ---------------------------------------------------------------------------
// MFMA GEMM: C[m][n] = sum_k A[m][k]*B[n][k].
// MODE 0: bf16 C. MODE 1: fp32 relu C. MODE 2: bf16 sigmoid(C + bias[m][n]).
// XCD-aware bijective swizzle (m204): each XCD owns a contiguous batch-major
// chunk of blocks so operand-panel re-reads hit that XCD's private L2.
// Final GEMM: nwg=768 -> exactly one batch per XCD.
// ---------------------------------------------------------------------------
template <int MODE>
__global__ __launch_bounds__(256) void mfma_gemm_bt(
    const unsigned short* __restrict__ A, const unsigned short* __restrict__ B,
    void* __restrict__ Cv, const float* __restrict__ bias, int K, int CN,
    long long Abatch, long long Bbatch, long long Cbatch) {
  __shared__ unsigned short As[128 * 64];
  __shared__ unsigned short Bs[128 * 64];
  int gx = gridDim.x, gy = gridDim.y;
  int nwg = gx * gy * gridDim.z;
  int bid = blockIdx.x + gx * (blockIdx.y + gy * blockIdx.z);
  int xcd = bid & 7, idx = bid >> 3;
  int qq = nwg >> 3, rr = nwg & 7;
  int lin = (xcd < rr ? xcd * (qq + 1) : rr * (qq + 1) + (xcd - rr) * qq) + idx;
  int b = lin / (gx * gy);
  int rem = lin - b * (gx * gy);
  int by = rem / gx, bx = rem - by * gx;
  int tid = threadIdx.x, wave = tid >> 6, lane = tid & 63;
  const unsigned short* Ag = A + (size_t)b * Abatch + (size_t)by * 128 * K;
  const unsigned short* Bg = B + (size_t)b * Bbatch + (size_t)bx * 128 * K;
  f32x4 zero = {0.f, 0.f, 0.f, 0.f};
  f32x4 acc[4][4];
  #pragma unroll
  for (int i = 0; i < 4; ++i)
    #pragma unroll
    for (int j = 0; j < 4; ++j) acc[i][j] = zero;
  gemm_core(Ag, Bg, K, K, K, As, Bs, wave, lane, acc);
  int rw = (wave >> 1) * 64, cw = (wave & 1) * 64;
  int q = lane >> 4, cl = lane & 15;
  #pragma unroll
  for (int i = 0; i < 4; ++i)
    #pragma unroll
    for (int e = 0; e < 4; ++e) {
      size_t P = (size_t)by * 128 + rw + i * 16 + q * 4 + e;
      #pragma unroll
      for (int j = 0; j < 4; ++j) {
        size_t Q = (size_t)bx * 128 + cw + j * 16 + cl;
        if (MODE == 0) {
          ((unsigned short*)Cv)[(size_t)b * Cbatch + P * CN + Q] = f2bf(acc[i][j][e]);
        } else if (MODE == 1) {
          ((float*)Cv)[(size_t)b * Cbatch + P * CN + Q] = fmaxf(acc[i][j][e], 0.f);
        } else {
          float v = acc[i][j][e] + bias[P * CN + Q];
          ((unsigned short*)Cv)[(size_t)b * Cbatch + P * CN + Q] =
              f2bf(1.f / (1.f + __expf(-v)));
        }
      }
    }
}

// ---------------------------------------------------------------------------
// y2 GEMM: for z=(bl,t): ycat[bl][(o*24+t)][k*1024+n] =
//   sum_f tcat[(k*64+o)][f] * xt2[bbase+bl][n][t][f].  K=64.
// ---------------------------------------------------------------------------
__global__ __launch_bounds__(256) void y2_gemm(
    const unsigned short* __restrict__ tcat, const unsigned short* __restrict__ xt2,
    unsigned short* __restrict__ ycat, int bbase) {
  __shared__ unsigned short As[128 * 64];
  __shared__ unsigned short Bs[128 * 64];
  int z = blockIdx.z;
  int bl = z / 24, t = z - bl * 24;
  int tid = threadIdx.x, wave = tid >> 6, lane = tid & 63;
  const unsigned short* Ag = tcat + (size_t)blockIdx.y * 128 * 64;
  const unsigned short* Bg = xt2 + ((size_t)(bbase + bl) * Nc + (size_t)blockIdx.x * 128) * Cc
                             + (size_t)t * 64;
  f32x4 zero = {0.f, 0.f, 0.f, 0.f};
  f32x4 acc[4][4];
  #pragma unroll
  for (int i = 0; i < 4; ++i)
    #pragma unroll
    for (int j = 0; j < 4; ++j) acc[i][j] = zero;
  gemm_core(Ag, Bg, 64, Cc, 64, As, Bs, wave, lane, acc);
  int rw = (wave >> 1) * 64, cw = (wave & 1) * 64;
  int q = lane >> 4, cl = lane & 15;
  unsigned short* yb = ycat + (size_t)bl * Cc * KKc + (size_t)t * KKc;
  #pragma unroll
  for (int i = 0; i < 4; ++i)
    #pragma unroll
    for (int e = 0; e < 4; ++e) {
      int m2 = blockIdx.y * 128 + rw + i * 16 + q * 4 + e;
      if (m2 < 192) {
        int kk = m2 >> 6, o = m2 & 63;
        unsigned short* dst = yb + (size_t)o * 24 * KKc + kk * Nc;
        #pragma unroll
        for (int j = 0; j < 4; ++j)
          dst[blockIdx.x * 128 + cw + j * 16 + cl] = f2bf(acc[i][j][e]);
      }
    }
}

// ---------------------------------------------------------------------------
extern "C" void kernel_launch(void* const* d_in, const int* in_sizes, int n_in,
                              void* d_out, int out_size, void* d_ws, size_t ws_size,
                              hipStream_t stream) {
  const float* x     = (const float*)d_in[0];
  const float* W1    = (const float*)d_in[1];
  const float* W2    = (const float*)d_in[2];
  const float* W3    = (const float*)d_in[3];
  const float* bs    = (const float*)d_in[4];
  const float* Vs    = (const float*)d_in[5];
  const float* cheb  = (const float*)d_in[6];
  const float* Theta = (const float*)d_in[7];
  float* out = (float*)d_out;

  // ws_size-adaptive: 1 pass of 16 batches (needs 348.2 MB) or 2 passes of 8
  // (needs 222.3 MB, the R4-verified layout). Deterministic per harness.
  int passes, blcount;
  if (ws_size >= 348160000ULL) { passes = 1; blcount = 16; }
  else                         { passes = 2; blcount = 8;  }

  char* w = (char*)d_ws;
  size_t Y  = (size_t)blcount * Cc * KKc * 2;   // ycat bytes
  size_t A2 = (size_t)blcount * Nc * KKc * 2;   // Acat bytes
  unsigned short* ycat = (unsigned short*)w;
  unsigned short* Acat = (unsigned short*)(w + Y);
  unsigned short* ST   = (unsigned short*)(w + Y + A2);                 // 33.55 MB
  float* chebT         = (float*)(w + Y + A2 + 33554432);               // 12.58 MB
  unsigned short* xt2  = (unsigned short*)(w + Y + A2 + 46137344);      // 50.33 MB
  unsigned short* tcat = (unsigned short*)(w + Y + A2 + 96468992);      // 32 KB
  // Front-phase temps aliased into ycat (all dead before y2 writes ycat):
  unsigned short* lhsb = (unsigned short*)w;                // 2 MB
  unsigned short* rhsb = (unsigned short*)(w + 2097152);    // 2 MB
  unsigned short* sigT = (unsigned short*)(w + 4194304);    // 33.55 MB
  float* bsT           = (float*)(w + 37748736);            // 4.19 MB
  unsigned short* Vsbf = (unsigned short*)(w + 41943040);   // 2 MB (ends 44.04 MB <= 75.5)

  xprep_kernel<<<Bc * Nc / 4, 256, 0, stream>>>(x, W1, W2, W3, xt2, lhsb, rhsb);
  misc_kernel<<<1344, 256, 0, stream>>>(Vs, Theta, bs, Vsbf, tcat, bsT);
  // sigT[p][q] = sigmoid(sum_t rhsb[p,t]*lhsb[q,t] + bsT[p][q])
  mfma_gemm_bt<2><<<dim3(8, 8, 16), 256, 0, stream>>>(
      rhsb, lhsb, sigT, bsT, 64, Nc,
      (long long)Nc * 64, (long long)Nc * 64, (long long)Nc * Nc);
  // ST[b][j][i] = sum_kk sigT[b][j][kk] * Vs[i][kk]
  mfma_gemm_bt<0><<<dim3(8, 8, 16), 256, 0, stream>>>(
      sigT, Vsbf, ST, nullptr, Nc, Nc,
      (long long)Nc * Nc, 0LL, (long long)Nc * Nc);
  chebT_kernel<<<dim3(16, 16, 3), 256, 0, stream>>>(cheb, chebT);

  for (int pass = 0; pass < passes; ++pass) {
    int bbase = pass * blcount;
    masksoft_kernel<<<blcount * Nc, 256, 0, stream>>>(chebT, ST, Acat, bbase);
    y2_gemm<<<dim3(Nc / 128, 2, blcount * 24), 256, 0, stream>>>(tcat, xt2, ycat, bbase);
    // out[b][m][o*24+t] = relu( sum_{kk<3072} Acat[bl][m][kk] * ycat[bl][c''][kk] )
    mfma_gemm_bt<1><<<dim3(Cc / 128, Nc / 128, blcount), 256, 0, stream>>>(
        Acat, ycat, out + (size_t)bbase * Nc * Cc, nullptr, KKc, Cc,
        (long long)Nc * KKc, (long long)Cc * KKc, (long long)Nc * Cc);
  }
}